// Round 1
// baseline (2059.256 us; speedup 1.0000x reference)
//
#include <hip/hip_runtime.h>

#define N_NODES 50000
#define N_EDGES 800000
#define NF 128   // node feature dim (IN_F == HID == OUT_F)
#define EH 32    // edge hidden

// ---------------- utility ----------------
__global__ void k_zero(float* __restrict__ p, int n) {
  int i = blockIdx.x * blockDim.x + threadIdx.x;
  if (i < n) p[i] = 0.f;
}

__global__ void k_count(const int* __restrict__ dst, float* __restrict__ deg, int E) {
  int e = blockIdx.x * blockDim.x + threadIdx.x;
  if (e < E) atomicAdd(&deg[dst[e]], 1.0f);
}

__global__ void k_inv(float* __restrict__ deg, int n) {
  int i = blockIdx.x * blockDim.x + threadIdx.x;
  if (i < n) deg[i] = 1.0f / fmaxf(deg[i], 1.0f);
}

// ---------------- scatter-add: agg[dst] += h[src], feature-parallel ----------------
__global__ __launch_bounds__(256) void k_scatter(
    const float* __restrict__ h, const int* __restrict__ src,
    const int* __restrict__ dst, float* __restrict__ agg, int E) {
  int idx = blockIdx.x * 256 + threadIdx.x;   // E*128 = 102.4M < 2^31
  int e = idx >> 7;
  int f = idx & 127;
  if (e < E) {
    int s = src[e], d = dst[e];
    atomicAdd(&agg[d * NF + f], h[s * NF + f]);
  }
}

// ---------------- fused SAGE GEMM: out = act(h@Ws + (agg*invdeg)@Wn + b) ----------------
// Tile 64x64, block 256 (16x16 threads, 4x4 microtile), BK=32, K=128 per matrix.
__global__ __launch_bounds__(256) void k_sage(
    const float* __restrict__ h, const float* __restrict__ agg,
    const float* __restrict__ invdeg,
    const float* __restrict__ Ws, const float* __restrict__ Wn,
    const float* __restrict__ bias,
    float* __restrict__ out, int M, int do_relu) {
  __shared__ float As[32][68];  // [k][row], row-pad 68 floats (272B, 16B-mult)
  __shared__ float Bs[32][68];  // [k][col]
  int row0 = blockIdx.x * 64;
  int col0 = blockIdx.y * 64;
  int tid = threadIdx.x;
  int tx = tid & 15, ty = tid >> 4;
  float acc[4][4] = {{0.f}};

  int aRow = tid >> 3;        // 0..31
  int ak = (tid & 7) * 4;     // 0..28
  int bk = tid >> 4;          // 0..15
  int bj = (tid & 15) * 4;    // 0..60

  for (int mat = 0; mat < 2; ++mat) {
    const float* __restrict__ A = mat ? agg : h;
    const float* __restrict__ W = mat ? Wn : Ws;
    for (int k0 = 0; k0 < NF; k0 += 32) {
      #pragma unroll
      for (int rr = 0; rr < 2; ++rr) {
        int r = aRow + rr * 32;
        int grow = row0 + r;
        float4 v = make_float4(0.f, 0.f, 0.f, 0.f);
        if (grow < M) {
          v = *(const float4*)&A[grow * NF + k0 + ak];
          if (mat) {
            float s = invdeg[grow];
            v.x *= s; v.y *= s; v.z *= s; v.w *= s;
          }
        }
        As[ak + 0][r] = v.x; As[ak + 1][r] = v.y;
        As[ak + 2][r] = v.z; As[ak + 3][r] = v.w;
      }
      #pragma unroll
      for (int rr = 0; rr < 2; ++rr) {
        int kk = bk + rr * 16;
        float4 v = *(const float4*)&W[(k0 + kk) * NF + col0 + bj];
        Bs[kk][bj + 0] = v.x; Bs[kk][bj + 1] = v.y;
        Bs[kk][bj + 2] = v.z; Bs[kk][bj + 3] = v.w;
      }
      __syncthreads();
      #pragma unroll
      for (int k = 0; k < 32; ++k) {
        float4 a4 = *(const float4*)&As[k][ty * 4];
        float4 b4 = *(const float4*)&Bs[k][tx * 4];
        float a[4] = {a4.x, a4.y, a4.z, a4.w};
        float b[4] = {b4.x, b4.y, b4.z, b4.w};
        #pragma unroll
        for (int i = 0; i < 4; ++i)
          #pragma unroll
          for (int j = 0; j < 4; ++j) acc[i][j] += a[i] * b[j];
      }
      __syncthreads();
    }
  }
  #pragma unroll
  for (int i = 0; i < 4; ++i) {
    int grow = row0 + ty * 4 + i;
    if (grow >= M) continue;
    #pragma unroll
    for (int j = 0; j < 4; ++j) {
      int col = col0 + tx * 4 + j;
      float v = acc[i][j] + bias[col];
      if (do_relu) v = fmaxf(v, 0.f);
      out[grow * NF + col] = v;
    }
  }
}

// ---------------- node-level edge projections: hu = h@Wu, hv = h@Wv ----------------
// block 256: 32 rows x 32 cols, each thread 4 rows x 1 col x 2 matrices
__global__ __launch_bounds__(256) void k_huv(
    const float* __restrict__ h, const float* __restrict__ wu,
    const float* __restrict__ wv, float* __restrict__ hu,
    float* __restrict__ hv, int M) {
  __shared__ float su[NF][33];
  __shared__ float sv[NF][33];
  __shared__ float sh[32][129];
  int tid = threadIdx.x;
  for (int i = tid; i < NF * EH; i += 256) {
    int k = i >> 5, c = i & 31;
    su[k][c] = wu[i];
    sv[k][c] = wv[i];
  }
  int row0 = blockIdx.x * 32;
  {
    int r = tid >> 3;         // 0..31
    int kk = (tid & 7) * 16;  // 4 float4 each
    int grow = row0 + r;
    if (grow < M) {
      #pragma unroll
      for (int q = 0; q < 4; ++q) {
        float4 v = *(const float4*)&h[grow * NF + kk + q * 4];
        sh[r][kk + q * 4 + 0] = v.x; sh[r][kk + q * 4 + 1] = v.y;
        sh[r][kk + q * 4 + 2] = v.z; sh[r][kk + q * 4 + 3] = v.w;
      }
    } else {
      #pragma unroll
      for (int q = 0; q < 16; ++q) sh[r][kk + q] = 0.f;
    }
  }
  __syncthreads();
  int c = tid & 31;
  int r0 = tid >> 5;  // 0..7 -> rows r0, r0+8, r0+16, r0+24
  float au[4] = {0.f, 0.f, 0.f, 0.f};
  float av[4] = {0.f, 0.f, 0.f, 0.f};
  #pragma unroll
  for (int k = 0; k < NF; ++k) {
    float xu = su[k][c], xv = sv[k][c];
    #pragma unroll
    for (int rr = 0; rr < 4; ++rr) {
      float x = sh[r0 + rr * 8][k];
      au[rr] += x * xu;
      av[rr] += x * xv;
    }
  }
  #pragma unroll
  for (int rr = 0; rr < 4; ++rr) {
    int grow = row0 + r0 + rr * 8;
    if (grow < M) {
      hu[grow * EH + c] = au[rr];
      hv[grow * EH + c] = av[rr];
    }
  }
}

// ---------------- edge MLP: out4 = relu(hu[src]+hv[dst]+ef@We+b)@W2 + b2 ----------------
template <int EFD>
__global__ __launch_bounds__(256) void k_edge(
    const float* __restrict__ hu, const float* __restrict__ hv,
    const int* __restrict__ src, const int* __restrict__ dst,
    const float* __restrict__ ef, int ef_stride,
    const float* __restrict__ we, const float* __restrict__ b,
    const float* __restrict__ w2, const float* __restrict__ b2,
    float* __restrict__ out, int out_col,
    const float* __restrict__ copy_ef, int E) {
  __shared__ float swe[EFD][EH];
  __shared__ float sw2[EH][4];
  __shared__ float sb[EH];
  __shared__ float sb2[4];
  int tid = threadIdx.x;
  for (int i = tid; i < EFD * EH; i += 256) swe[i >> 5][i & 31] = we[i];
  if (tid < EH * 4) sw2[tid >> 2][tid & 3] = w2[tid];
  if (tid < EH) sb[tid] = b[tid];
  if (tid < 4) sb2[tid] = b2[tid];
  __syncthreads();
  int e = blockIdx.x * 256 + tid;
  if (e >= E) return;
  int s = src[e], d = dst[e];
  const float4* pu = (const float4*)&hu[s * EH];
  const float4* pv = (const float4*)&hv[d * EH];
  float efv[EFD];
  #pragma unroll
  for (int i = 0; i < EFD; ++i) efv[i] = ef[(long long)e * ef_stride + i];
  float t[EH];
  #pragma unroll
  for (int q = 0; q < EH / 4; ++q) {
    float4 a = pu[q];
    float4 bv = pv[q];
    t[q * 4 + 0] = a.x + bv.x;
    t[q * 4 + 1] = a.y + bv.y;
    t[q * 4 + 2] = a.z + bv.z;
    t[q * 4 + 3] = a.w + bv.w;
  }
  #pragma unroll
  for (int c = 0; c < EH; ++c) {
    float v = t[c] + sb[c];
    #pragma unroll
    for (int i = 0; i < EFD; ++i) v += efv[i] * swe[i][c];
    t[c] = fmaxf(v, 0.f);
  }
  float o[4] = {sb2[0], sb2[1], sb2[2], sb2[3]};
  #pragma unroll
  for (int c = 0; c < EH; ++c) {
    #pragma unroll
    for (int j = 0; j < 4; ++j) o[j] += t[c] * sw2[c][j];
  }
  *(float4*)&out[(long long)e * 12 + out_col] = make_float4(o[0], o[1], o[2], o[3]);
  if (copy_ef) *(float4*)&out[(long long)e * 12] = *(const float4*)&copy_ef[e * 4];
}

// ---------------- launch ----------------
extern "C" void kernel_launch(void* const* d_in, const int* in_sizes, int n_in,
                              void* d_out, int out_size, void* d_ws, size_t ws_size,
                              hipStream_t stream) {
  const float* inputs    = (const float*)d_in[0];
  const float* edge_feat = (const float*)d_in[1];
  const float* w_self1   = (const float*)d_in[2];
  const float* w_neigh1  = (const float*)d_in[3];
  const float* b_conv1   = (const float*)d_in[4];
  const float* eu1_wu    = (const float*)d_in[5];
  const float* eu1_wv    = (const float*)d_in[6];
  const float* eu1_we    = (const float*)d_in[7];
  const float* eu1_b     = (const float*)d_in[8];
  const float* eu1_w2    = (const float*)d_in[9];
  const float* eu1_b2    = (const float*)d_in[10];
  const float* w_self2   = (const float*)d_in[11];
  const float* w_neigh2  = (const float*)d_in[12];
  const float* b_conv2   = (const float*)d_in[13];
  const float* eu2_wu    = (const float*)d_in[14];
  const float* eu2_wv    = (const float*)d_in[15];
  const float* eu2_we    = (const float*)d_in[16];
  const float* eu2_b     = (const float*)d_in[17];
  const float* eu2_w2    = (const float*)d_in[18];
  const float* eu2_b2    = (const float*)d_in[19];
  const float* w_self3   = (const float*)d_in[20];
  const float* w_neigh3  = (const float*)d_in[21];
  const float* b_conv3   = (const float*)d_in[22];
  const int*   esrc      = (const int*)d_in[23];
  const int*   edst      = (const int*)d_in[24];

  float* out_h  = (float*)d_out;                          // [N,128]
  float* out_ef = (float*)d_out + (long long)N_NODES * NF; // [E,12]

  float* ws  = (float*)d_ws;
  float* deg = ws;                              // N (reserve 65536)
  float* agg = ws + 65536;                      // N*128
  float* hA  = agg + (long long)N_NODES * NF;   // N*128
  float* hB  = hA + (long long)N_NODES * NF;    // N*128
  float* hu  = hB + (long long)N_NODES * NF;    // N*32
  float* hv  = hu + (long long)N_NODES * EH;    // N*32

  const int N = N_NODES, E = N_EDGES;
  dim3 gsage((N + 63) / 64, 2);
  int scat_blocks = (E * NF) / 256;            // 102.4M threads exactly
  int aggN = N * NF;

  // degrees (shared across all 3 layers)
  k_zero<<<(N + 255) / 256, 256, 0, stream>>>(deg, N);
  k_count<<<(E + 255) / 256, 256, 0, stream>>>(edst, deg, E);
  k_inv<<<(N + 255) / 256, 256, 0, stream>>>(deg, N);

  // ---- layer 1
  k_zero<<<(aggN + 255) / 256, 256, 0, stream>>>(agg, aggN);
  k_scatter<<<scat_blocks, 256, 0, stream>>>(inputs, esrc, edst, agg, E);
  k_sage<<<gsage, 256, 0, stream>>>(inputs, agg, deg, w_self1, w_neigh1, b_conv1, hA, N, 1);
  k_huv<<<(N + 31) / 32, 256, 0, stream>>>(hA, eu1_wu, eu1_wv, hu, hv, N);
  k_edge<4><<<(E + 255) / 256, 256, 0, stream>>>(
      hu, hv, esrc, edst, edge_feat, 4, eu1_we, eu1_b, eu1_w2, eu1_b2,
      out_ef, 4, edge_feat, E);

  // ---- layer 2
  k_zero<<<(aggN + 255) / 256, 256, 0, stream>>>(agg, aggN);
  k_scatter<<<scat_blocks, 256, 0, stream>>>(hA, esrc, edst, agg, E);
  k_sage<<<gsage, 256, 0, stream>>>(hA, agg, deg, w_self2, w_neigh2, b_conv2, hB, N, 1);
  k_huv<<<(N + 31) / 32, 256, 0, stream>>>(hB, eu2_wu, eu2_wv, hu, hv, N);
  k_edge<8><<<(E + 255) / 256, 256, 0, stream>>>(
      hu, hv, esrc, edst, out_ef, 12, eu2_we, eu2_b, eu2_w2, eu2_b2,
      out_ef, 8, nullptr, E);

  // ---- layer 3 (no relu, output directly)
  k_zero<<<(aggN + 255) / 256, 256, 0, stream>>>(agg, aggN);
  k_scatter<<<scat_blocks, 256, 0, stream>>>(hB, esrc, edst, agg, E);
  k_sage<<<gsage, 256, 0, stream>>>(hB, agg, deg, w_self3, w_neigh3, b_conv3, out_h, N, 0);
}

// Round 2
// 782.376 us; speedup vs baseline: 2.6321x; 2.6321x over previous
//
#include <hip/hip_runtime.h>

#define N_NODES 50000
#define N_EDGES 800000
#define NF 128   // node feature dim (IN_F == HID == OUT_F)
#define EH 32    // edge hidden

// ---------------- CSR build ----------------
__global__ void k_zeroi(int* __restrict__ p, int n) {
  int i = blockIdx.x * blockDim.x + threadIdx.x;
  if (i < n) p[i] = 0;
}

__global__ void k_counti(const int* __restrict__ dst, int* __restrict__ cnt, int E) {
  int e = blockIdx.x * blockDim.x + threadIdx.x;
  if (e < E) atomicAdd(&cnt[dst[e]], 1);
}

// one block, 1024 threads: exclusive scan of cnt[0..N) -> rowptr[0..N], cursor copy
__global__ __launch_bounds__(1024) void k_scan(const int* __restrict__ cnt,
                                               int* __restrict__ rowptr,
                                               int* __restrict__ cursor) {
  __shared__ int part[1024];
  int t = threadIdx.x;
  const int CH = 49;  // 1024*49 = 50176 >= 50000
  int base = t * CH;
  int s = 0;
  for (int i = 0; i < CH; ++i) {
    int idx = base + i;
    if (idx < N_NODES) s += cnt[idx];
  }
  part[t] = s;
  __syncthreads();
  for (int off = 1; off < 1024; off <<= 1) {
    int v = (t >= off) ? part[t - off] : 0;
    __syncthreads();
    part[t] += v;
    __syncthreads();
  }
  int run = part[t] - s;  // exclusive prefix for this chunk
  for (int i = 0; i < CH; ++i) {
    int idx = base + i;
    if (idx < N_NODES) {
      int c = cnt[idx];
      rowptr[idx] = run;
      cursor[idx] = run;
      run += c;
    }
  }
  if (t == 1023) rowptr[N_NODES] = run;  // = E
}

__global__ void k_fill(const int* __restrict__ src, const int* __restrict__ dst,
                       int* __restrict__ cursor, int* __restrict__ csr_src, int E) {
  int e = blockIdx.x * blockDim.x + threadIdx.x;
  if (e < E) {
    int p = atomicAdd(&cursor[dst[e]], 1);
    csr_src[p] = src[e];
  }
}

// ---------------- CSR mean-gather: agg[n] = mean over in-edges of h[src] ----------------
__global__ __launch_bounds__(128) void k_gather(
    const float* __restrict__ h, const int* __restrict__ rowptr,
    const int* __restrict__ csr_src, float* __restrict__ agg) {
  int n = blockIdx.x;
  int f = threadIdx.x;
  int beg = rowptr[n], end = rowptr[n + 1];
  float a0 = 0.f, a1 = 0.f, a2 = 0.f, a3 = 0.f;
  int j = beg;
  for (; j + 4 <= end; j += 4) {
    int s0 = csr_src[j + 0], s1 = csr_src[j + 1];
    int s2 = csr_src[j + 2], s3 = csr_src[j + 3];
    a0 += h[s0 * NF + f];
    a1 += h[s1 * NF + f];
    a2 += h[s2 * NF + f];
    a3 += h[s3 * NF + f];
  }
  for (; j < end; ++j) a0 += h[csr_src[j] * NF + f];
  int deg = end - beg;
  float inv = deg > 0 ? 1.0f / (float)deg : 0.f;
  agg[n * NF + f] = (a0 + a1 + a2 + a3) * inv;
}

// ---------------- fused SAGE GEMM: out = act(h@Ws + agg@Wn + b) ----------------
// agg is pre-averaged. Tile 64x64, block 256 (16x16 threads, 4x4 microtile), BK=32.
__global__ __launch_bounds__(256) void k_sage(
    const float* __restrict__ h, const float* __restrict__ agg,
    const float* __restrict__ Ws, const float* __restrict__ Wn,
    const float* __restrict__ bias,
    float* __restrict__ out, int M, int do_relu) {
  __shared__ float As[32][68];  // [k][row]
  __shared__ float Bs[32][68];  // [k][col]
  int row0 = blockIdx.x * 64;
  int col0 = blockIdx.y * 64;
  int tid = threadIdx.x;
  int tx = tid & 15, ty = tid >> 4;
  float acc[4][4] = {{0.f}};

  int aRow = tid >> 3;        // 0..31
  int ak = (tid & 7) * 4;     // 0..28
  int bk = tid >> 4;          // 0..15
  int bj = (tid & 15) * 4;    // 0..60

  for (int mat = 0; mat < 2; ++mat) {
    const float* __restrict__ A = mat ? agg : h;
    const float* __restrict__ W = mat ? Wn : Ws;
    for (int k0 = 0; k0 < NF; k0 += 32) {
      #pragma unroll
      for (int rr = 0; rr < 2; ++rr) {
        int r = aRow + rr * 32;
        int grow = row0 + r;
        float4 v = make_float4(0.f, 0.f, 0.f, 0.f);
        if (grow < M) v = *(const float4*)&A[grow * NF + k0 + ak];
        As[ak + 0][r] = v.x; As[ak + 1][r] = v.y;
        As[ak + 2][r] = v.z; As[ak + 3][r] = v.w;
      }
      #pragma unroll
      for (int rr = 0; rr < 2; ++rr) {
        int kk = bk + rr * 16;
        float4 v = *(const float4*)&W[(k0 + kk) * NF + col0 + bj];
        Bs[kk][bj + 0] = v.x; Bs[kk][bj + 1] = v.y;
        Bs[kk][bj + 2] = v.z; Bs[kk][bj + 3] = v.w;
      }
      __syncthreads();
      #pragma unroll
      for (int k = 0; k < 32; ++k) {
        float4 a4 = *(const float4*)&As[k][ty * 4];
        float4 b4 = *(const float4*)&Bs[k][tx * 4];
        float a[4] = {a4.x, a4.y, a4.z, a4.w};
        float b[4] = {b4.x, b4.y, b4.z, b4.w};
        #pragma unroll
        for (int i = 0; i < 4; ++i)
          #pragma unroll
          for (int j = 0; j < 4; ++j) acc[i][j] += a[i] * b[j];
      }
      __syncthreads();
    }
  }
  #pragma unroll
  for (int i = 0; i < 4; ++i) {
    int grow = row0 + ty * 4 + i;
    if (grow >= M) continue;
    #pragma unroll
    for (int j = 0; j < 4; ++j) {
      int col = col0 + tx * 4 + j;
      float v = acc[i][j] + bias[col];
      if (do_relu) v = fmaxf(v, 0.f);
      out[grow * NF + col] = v;
    }
  }
}

// ---------------- node-level edge projections: [hu|hv] = h @ [Wu|Wv] ----------------
// Same tile structure as k_sage: 64 rows x 64 cols (32 hu + 32 hv), K=128.
__global__ __launch_bounds__(256) void k_proj(
    const float* __restrict__ h, const float* __restrict__ wu,
    const float* __restrict__ wv, float* __restrict__ hu,
    float* __restrict__ hv, int M) {
  __shared__ float As[32][68];
  __shared__ float Bs[32][68];
  int row0 = blockIdx.x * 64;
  int tid = threadIdx.x;
  int tx = tid & 15, ty = tid >> 4;
  float acc[4][4] = {{0.f}};

  int aRow = tid >> 3;
  int ak = (tid & 7) * 4;
  int bk = tid >> 4;
  int bj = (tid & 15) * 4;

  for (int k0 = 0; k0 < NF; k0 += 32) {
    #pragma unroll
    for (int rr = 0; rr < 2; ++rr) {
      int r = aRow + rr * 32;
      int grow = row0 + r;
      float4 v = make_float4(0.f, 0.f, 0.f, 0.f);
      if (grow < M) v = *(const float4*)&h[grow * NF + k0 + ak];
      As[ak + 0][r] = v.x; As[ak + 1][r] = v.y;
      As[ak + 2][r] = v.z; As[ak + 3][r] = v.w;
    }
    #pragma unroll
    for (int rr = 0; rr < 2; ++rr) {
      int kk = bk + rr * 16;
      const float* W = (bj < 32) ? &wu[(k0 + kk) * EH + bj]
                                 : &wv[(k0 + kk) * EH + bj - 32];
      float4 v = *(const float4*)W;
      Bs[kk][bj + 0] = v.x; Bs[kk][bj + 1] = v.y;
      Bs[kk][bj + 2] = v.z; Bs[kk][bj + 3] = v.w;
    }
    __syncthreads();
    #pragma unroll
    for (int k = 0; k < 32; ++k) {
      float4 a4 = *(const float4*)&As[k][ty * 4];
      float4 b4 = *(const float4*)&Bs[k][tx * 4];
      float a[4] = {a4.x, a4.y, a4.z, a4.w};
      float b[4] = {b4.x, b4.y, b4.z, b4.w};
      #pragma unroll
      for (int i = 0; i < 4; ++i)
        #pragma unroll
        for (int j = 0; j < 4; ++j) acc[i][j] += a[i] * b[j];
    }
    __syncthreads();
  }
  #pragma unroll
  for (int i = 0; i < 4; ++i) {
    int grow = row0 + ty * 4 + i;
    if (grow >= M) continue;
    float4 o = make_float4(acc[i][0], acc[i][1], acc[i][2], acc[i][3]);
    int col = tx * 4;
    if (col < 32) *(float4*)&hu[grow * EH + col] = o;
    else          *(float4*)&hv[grow * EH + col - 32] = o;
  }
}

// ---------------- edge MLP: out4 = relu(hu[src]+hv[dst]+ef@We+b)@W2 + b2 ----------------
template <int EFD>
__global__ __launch_bounds__(256) void k_edge(
    const float* __restrict__ hu, const float* __restrict__ hv,
    const int* __restrict__ src, const int* __restrict__ dst,
    const float* __restrict__ ef, int ef_stride,
    const float* __restrict__ we, const float* __restrict__ b,
    const float* __restrict__ w2, const float* __restrict__ b2,
    float* __restrict__ out, int out_col,
    const float* __restrict__ copy_ef, int E) {
  __shared__ float swe[EFD][EH];
  __shared__ float sw2[EH][4];
  __shared__ float sb[EH];
  __shared__ float sb2[4];
  int tid = threadIdx.x;
  for (int i = tid; i < EFD * EH; i += 256) swe[i >> 5][i & 31] = we[i];
  if (tid < EH * 4) sw2[tid >> 2][tid & 3] = w2[tid];
  if (tid < EH) sb[tid] = b[tid];
  if (tid < 4) sb2[tid] = b2[tid];
  __syncthreads();
  int e = blockIdx.x * 256 + tid;
  if (e >= E) return;
  int s = src[e], d = dst[e];
  const float4* pu = (const float4*)&hu[s * EH];
  const float4* pv = (const float4*)&hv[d * EH];
  float efv[EFD];
  #pragma unroll
  for (int i = 0; i < EFD; ++i) efv[i] = ef[(long long)e * ef_stride + i];
  float t[EH];
  #pragma unroll
  for (int q = 0; q < EH / 4; ++q) {
    float4 a = pu[q];
    float4 bv = pv[q];
    t[q * 4 + 0] = a.x + bv.x;
    t[q * 4 + 1] = a.y + bv.y;
    t[q * 4 + 2] = a.z + bv.z;
    t[q * 4 + 3] = a.w + bv.w;
  }
  #pragma unroll
  for (int c = 0; c < EH; ++c) {
    float v = t[c] + sb[c];
    #pragma unroll
    for (int i = 0; i < EFD; ++i) v += efv[i] * swe[i][c];
    t[c] = fmaxf(v, 0.f);
  }
  float o[4] = {sb2[0], sb2[1], sb2[2], sb2[3]};
  #pragma unroll
  for (int c = 0; c < EH; ++c) {
    #pragma unroll
    for (int j = 0; j < 4; ++j) o[j] += t[c] * sw2[c][j];
  }
  *(float4*)&out[(long long)e * 12 + out_col] = make_float4(o[0], o[1], o[2], o[3]);
  if (copy_ef) *(float4*)&out[(long long)e * 12] = *(const float4*)&copy_ef[e * 4];
}

// ---------------- launch ----------------
extern "C" void kernel_launch(void* const* d_in, const int* in_sizes, int n_in,
                              void* d_out, int out_size, void* d_ws, size_t ws_size,
                              hipStream_t stream) {
  const float* inputs    = (const float*)d_in[0];
  const float* edge_feat = (const float*)d_in[1];
  const float* w_self1   = (const float*)d_in[2];
  const float* w_neigh1  = (const float*)d_in[3];
  const float* b_conv1   = (const float*)d_in[4];
  const float* eu1_wu    = (const float*)d_in[5];
  const float* eu1_wv    = (const float*)d_in[6];
  const float* eu1_we    = (const float*)d_in[7];
  const float* eu1_b     = (const float*)d_in[8];
  const float* eu1_w2    = (const float*)d_in[9];
  const float* eu1_b2    = (const float*)d_in[10];
  const float* w_self2   = (const float*)d_in[11];
  const float* w_neigh2  = (const float*)d_in[12];
  const float* b_conv2   = (const float*)d_in[13];
  const float* eu2_wu    = (const float*)d_in[14];
  const float* eu2_wv    = (const float*)d_in[15];
  const float* eu2_we    = (const float*)d_in[16];
  const float* eu2_b     = (const float*)d_in[17];
  const float* eu2_w2    = (const float*)d_in[18];
  const float* eu2_b2    = (const float*)d_in[19];
  const float* w_self3   = (const float*)d_in[20];
  const float* w_neigh3  = (const float*)d_in[21];
  const float* b_conv3   = (const float*)d_in[22];
  const int*   esrc      = (const int*)d_in[23];
  const int*   edst      = (const int*)d_in[24];

  float* out_h  = (float*)d_out;                           // [N,128]
  float* out_ef = (float*)d_out + (long long)N_NODES * NF; // [E,12]

  // workspace layout (ints first, 16B-aligned float region after)
  int* iws     = (int*)d_ws;
  int* rowptr  = iws;                 // N+1 (pad to 50004)
  int* cursor  = iws + 50004;         // N   (pad to 50004)
  int* cnt     = iws + 100008;        // N   (pad to 50008 -> next at 150016)
  int* csr_src = iws + 150016;        // E = 800000
  float* agg   = (float*)(iws + 950016);       // N*128 (byte off 3800064, %16==0)
  float* hA    = agg + (long long)N_NODES * NF;
  float* hB    = hA + (long long)N_NODES * NF;
  // hu/hv alias agg: agg is dead between k_sage (its last read) and the next
  // layer's k_gather (its next write); k_proj/k_edge run in that window.
  float* hu = agg;
  float* hv = agg + (long long)N_NODES * EH;

  const int N = N_NODES, E = N_EDGES;
  dim3 gsage((N + 63) / 64, 2);
  int gproj = (N + 63) / 64;

  // ---- CSR build (dst-sorted src list)
  k_zeroi<<<(N + 255) / 256, 256, 0, stream>>>(cnt, N);
  k_counti<<<(E + 255) / 256, 256, 0, stream>>>(edst, cnt, E);
  k_scan<<<1, 1024, 0, stream>>>(cnt, rowptr, cursor);
  k_fill<<<(E + 255) / 256, 256, 0, stream>>>(esrc, edst, cursor, csr_src, E);

  // ---- layer 1
  k_gather<<<N, 128, 0, stream>>>(inputs, rowptr, csr_src, agg);
  k_sage<<<gsage, 256, 0, stream>>>(inputs, agg, w_self1, w_neigh1, b_conv1, hA, N, 1);
  k_proj<<<gproj, 256, 0, stream>>>(hA, eu1_wu, eu1_wv, hu, hv, N);
  k_edge<4><<<(E + 255) / 256, 256, 0, stream>>>(
      hu, hv, esrc, edst, edge_feat, 4, eu1_we, eu1_b, eu1_w2, eu1_b2,
      out_ef, 4, edge_feat, E);

  // ---- layer 2
  k_gather<<<N, 128, 0, stream>>>(hA, rowptr, csr_src, agg);
  k_sage<<<gsage, 256, 0, stream>>>(hA, agg, w_self2, w_neigh2, b_conv2, hB, N, 1);
  k_proj<<<gproj, 256, 0, stream>>>(hB, eu2_wu, eu2_wv, hu, hv, N);
  k_edge<8><<<(E + 255) / 256, 256, 0, stream>>>(
      hu, hv, esrc, edst, out_ef, 12, eu2_we, eu2_b, eu2_w2, eu2_b2,
      out_ef, 8, nullptr, E);

  // ---- layer 3 (no relu, output directly)
  k_gather<<<N, 128, 0, stream>>>(hB, rowptr, csr_src, agg);
  k_sage<<<gsage, 256, 0, stream>>>(hB, agg, w_self3, w_neigh3, b_conv3, out_h, N, 0);
}

// Round 3
// 665.550 us; speedup vs baseline: 3.0941x; 1.1755x over previous
//
#include <hip/hip_runtime.h>

#define N_NODES 50000
#define N_EDGES 800000
#define NF 128   // node feature dim (IN_F == HID == OUT_F)
#define EH 32    // edge hidden
#define SCAN_NB 196  // ceil(50000/256)

// ---------------- CSR build ----------------
__global__ void k_zeroi(int* __restrict__ p, int n) {
  int i = blockIdx.x * blockDim.x + threadIdx.x;
  if (i < n) p[i] = 0;
}

__global__ void k_counti(const int* __restrict__ dst, int* __restrict__ cnt, int E) {
  int e = blockIdx.x * blockDim.x + threadIdx.x;
  if (e < E) atomicAdd(&cnt[dst[e]], 1);
}

// phase 1: per-block sums of cnt
__global__ __launch_bounds__(256) void k_bsum(const int* __restrict__ cnt,
                                              int* __restrict__ btot) {
  __shared__ int s[256];
  int t = threadIdx.x;
  int i = blockIdx.x * 256 + t;
  s[t] = (i < N_NODES) ? cnt[i] : 0;
  __syncthreads();
  #pragma unroll
  for (int off = 128; off > 0; off >>= 1) {
    if (t < off) s[t] += s[t + off];
    __syncthreads();
  }
  if (t == 0) btot[blockIdx.x] = s[0];
}

// phase 2: one block exclusive-scans the block sums (SCAN_NB <= 256)
__global__ __launch_bounds__(256) void k_bscan(int* __restrict__ btot) {
  __shared__ int s[256];
  int t = threadIdx.x;
  int v = (t < SCAN_NB) ? btot[t] : 0;
  s[t] = v;
  __syncthreads();
  #pragma unroll
  for (int off = 1; off < 256; off <<= 1) {
    int u = (t >= off) ? s[t - off] : 0;
    __syncthreads();
    s[t] += u;
    __syncthreads();
  }
  if (t < SCAN_NB) btot[t] = s[t] - v;  // exclusive
}

// phase 3: local scan + block offset -> exclusive rowptr & cursor
__global__ __launch_bounds__(256) void k_wrow(const int* __restrict__ cnt,
                                              const int* __restrict__ boffs,
                                              int* __restrict__ rowptr,
                                              int* __restrict__ cursor) {
  __shared__ int s[256];
  int t = threadIdx.x;
  int i = blockIdx.x * 256 + t;
  int v = (i < N_NODES) ? cnt[i] : 0;
  s[t] = v;
  __syncthreads();
  #pragma unroll
  for (int off = 1; off < 256; off <<= 1) {
    int u = (t >= off) ? s[t - off] : 0;
    __syncthreads();
    s[t] += u;
    __syncthreads();
  }
  if (i < N_NODES) {
    int ex = boffs[blockIdx.x] + s[t] - v;
    rowptr[i] = ex;
    cursor[i] = ex;
  }
  if (i == 0) rowptr[N_NODES] = N_EDGES;  // total degree is constant
}

__global__ void k_fill(const int* __restrict__ src, const int* __restrict__ dst,
                       int* __restrict__ cursor, int* __restrict__ csr_src, int E) {
  int e = blockIdx.x * blockDim.x + threadIdx.x;
  if (e < E) {
    int p = atomicAdd(&cursor[dst[e]], 1);
    csr_src[p] = src[e];
  }
}

// ---------------- CSR mean-gather: agg[n] = mean over in-edges of h[src] ----------------
__global__ __launch_bounds__(128) void k_gather(
    const float* __restrict__ h, const int* __restrict__ rowptr,
    const int* __restrict__ csr_src, float* __restrict__ agg) {
  int n = blockIdx.x;
  int f = threadIdx.x;
  int beg = rowptr[n], end = rowptr[n + 1];
  float a0 = 0.f, a1 = 0.f, a2 = 0.f, a3 = 0.f;
  int j = beg;
  for (; j + 4 <= end; j += 4) {
    int s0 = csr_src[j + 0], s1 = csr_src[j + 1];
    int s2 = csr_src[j + 2], s3 = csr_src[j + 3];
    a0 += h[s0 * NF + f];
    a1 += h[s1 * NF + f];
    a2 += h[s2 * NF + f];
    a3 += h[s3 * NF + f];
  }
  for (; j < end; ++j) a0 += h[csr_src[j] * NF + f];
  int deg = end - beg;
  float inv = deg > 0 ? 1.0f / (float)deg : 0.f;
  agg[n * NF + f] = (a0 + a1 + a2 + a3) * inv;
}

// ---------------- fused SAGE GEMM: out = act(h@Ws + agg@Wn + b) ----------------
__global__ __launch_bounds__(256) void k_sage(
    const float* __restrict__ h, const float* __restrict__ agg,
    const float* __restrict__ Ws, const float* __restrict__ Wn,
    const float* __restrict__ bias,
    float* __restrict__ out, int M, int do_relu) {
  __shared__ float As[32][68];  // [k][row]
  __shared__ float Bs[32][68];  // [k][col]
  int row0 = blockIdx.x * 64;
  int col0 = blockIdx.y * 64;
  int tid = threadIdx.x;
  int tx = tid & 15, ty = tid >> 4;
  float acc[4][4] = {{0.f}};

  int aRow = tid >> 3;        // 0..31
  int ak = (tid & 7) * 4;     // 0..28
  int bk = tid >> 4;          // 0..15
  int bj = (tid & 15) * 4;    // 0..60

  for (int mat = 0; mat < 2; ++mat) {
    const float* __restrict__ A = mat ? agg : h;
    const float* __restrict__ W = mat ? Wn : Ws;
    for (int k0 = 0; k0 < NF; k0 += 32) {
      #pragma unroll
      for (int rr = 0; rr < 2; ++rr) {
        int r = aRow + rr * 32;
        int grow = row0 + r;
        float4 v = make_float4(0.f, 0.f, 0.f, 0.f);
        if (grow < M) v = *(const float4*)&A[grow * NF + k0 + ak];
        As[ak + 0][r] = v.x; As[ak + 1][r] = v.y;
        As[ak + 2][r] = v.z; As[ak + 3][r] = v.w;
      }
      #pragma unroll
      for (int rr = 0; rr < 2; ++rr) {
        int kk = bk + rr * 16;
        float4 v = *(const float4*)&W[(k0 + kk) * NF + col0 + bj];
        Bs[kk][bj + 0] = v.x; Bs[kk][bj + 1] = v.y;
        Bs[kk][bj + 2] = v.z; Bs[kk][bj + 3] = v.w;
      }
      __syncthreads();
      #pragma unroll
      for (int k = 0; k < 32; ++k) {
        float4 a4 = *(const float4*)&As[k][ty * 4];
        float4 b4 = *(const float4*)&Bs[k][tx * 4];
        float a[4] = {a4.x, a4.y, a4.z, a4.w};
        float b[4] = {b4.x, b4.y, b4.z, b4.w};
        #pragma unroll
        for (int i = 0; i < 4; ++i)
          #pragma unroll
          for (int j = 0; j < 4; ++j) acc[i][j] += a[i] * b[j];
      }
      __syncthreads();
    }
  }
  #pragma unroll
  for (int i = 0; i < 4; ++i) {
    int grow = row0 + ty * 4 + i;
    if (grow >= M) continue;
    #pragma unroll
    for (int j = 0; j < 4; ++j) {
      int col = col0 + tx * 4 + j;
      float v = acc[i][j] + bias[col];
      if (do_relu) v = fmaxf(v, 0.f);
      out[grow * NF + col] = v;
    }
  }
}

// ---------------- node-level edge projections: [hu|hv] = h @ [Wu|Wv] ----------------
__global__ __launch_bounds__(256) void k_proj(
    const float* __restrict__ h, const float* __restrict__ wu,
    const float* __restrict__ wv, float* __restrict__ hu,
    float* __restrict__ hv, int M) {
  __shared__ float As[32][68];
  __shared__ float Bs[32][68];
  int row0 = blockIdx.x * 64;
  int tid = threadIdx.x;
  int tx = tid & 15, ty = tid >> 4;
  float acc[4][4] = {{0.f}};

  int aRow = tid >> 3;
  int ak = (tid & 7) * 4;
  int bk = tid >> 4;
  int bj = (tid & 15) * 4;

  for (int k0 = 0; k0 < NF; k0 += 32) {
    #pragma unroll
    for (int rr = 0; rr < 2; ++rr) {
      int r = aRow + rr * 32;
      int grow = row0 + r;
      float4 v = make_float4(0.f, 0.f, 0.f, 0.f);
      if (grow < M) v = *(const float4*)&h[grow * NF + k0 + ak];
      As[ak + 0][r] = v.x; As[ak + 1][r] = v.y;
      As[ak + 2][r] = v.z; As[ak + 3][r] = v.w;
    }
    #pragma unroll
    for (int rr = 0; rr < 2; ++rr) {
      int kk = bk + rr * 16;
      const float* W = (bj < 32) ? &wu[(k0 + kk) * EH + bj]
                                 : &wv[(k0 + kk) * EH + bj - 32];
      float4 v = *(const float4*)W;
      Bs[kk][bj + 0] = v.x; Bs[kk][bj + 1] = v.y;
      Bs[kk][bj + 2] = v.z; Bs[kk][bj + 3] = v.w;
    }
    __syncthreads();
    #pragma unroll
    for (int k = 0; k < 32; ++k) {
      float4 a4 = *(const float4*)&As[k][ty * 4];
      float4 b4 = *(const float4*)&Bs[k][tx * 4];
      float a[4] = {a4.x, a4.y, a4.z, a4.w};
      float b[4] = {b4.x, b4.y, b4.z, b4.w};
      #pragma unroll
      for (int i = 0; i < 4; ++i)
        #pragma unroll
        for (int j = 0; j < 4; ++j) acc[i][j] += a[i] * b[j];
    }
    __syncthreads();
  }
  #pragma unroll
  for (int i = 0; i < 4; ++i) {
    int grow = row0 + ty * 4 + i;
    if (grow >= M) continue;
    float4 o = make_float4(acc[i][0], acc[i][1], acc[i][2], acc[i][3]);
    int col = tx * 4;
    if (col < 32) *(float4*)&hu[grow * EH + col] = o;
    else          *(float4*)&hv[grow * EH + col - 32] = o;
  }
}

// ---------------- edge MLP: out4 = relu(hu[src]+hv[dst]+ef@We+b)@W2 + b2 ----------------
template <int EFD>
__global__ __launch_bounds__(256) void k_edge(
    const float* __restrict__ hu, const float* __restrict__ hv,
    const int* __restrict__ src, const int* __restrict__ dst,
    const float* __restrict__ ef, int ef_stride,
    const float* __restrict__ we, const float* __restrict__ b,
    const float* __restrict__ w2, const float* __restrict__ b2,
    float* __restrict__ out, int out_col,
    const float* __restrict__ copy_ef, int E) {
  __shared__ float swe[EFD][EH];
  __shared__ float sw2[EH][4];
  __shared__ float sb[EH];
  __shared__ float sb2[4];
  int tid = threadIdx.x;
  for (int i = tid; i < EFD * EH; i += 256) swe[i >> 5][i & 31] = we[i];
  if (tid < EH * 4) sw2[tid >> 2][tid & 3] = w2[tid];
  if (tid < EH) sb[tid] = b[tid];
  if (tid < 4) sb2[tid] = b2[tid];
  __syncthreads();
  int e = blockIdx.x * 256 + tid;
  if (e >= E) return;
  int s = src[e], d = dst[e];
  const float4* pu = (const float4*)&hu[s * EH];
  const float4* pv = (const float4*)&hv[d * EH];
  float efv[EFD];
  #pragma unroll
  for (int i = 0; i < EFD; ++i) efv[i] = ef[(long long)e * ef_stride + i];
  float t[EH];
  #pragma unroll
  for (int q = 0; q < EH / 4; ++q) {
    float4 a = pu[q];
    float4 bv = pv[q];
    t[q * 4 + 0] = a.x + bv.x;
    t[q * 4 + 1] = a.y + bv.y;
    t[q * 4 + 2] = a.z + bv.z;
    t[q * 4 + 3] = a.w + bv.w;
  }
  #pragma unroll
  for (int c = 0; c < EH; ++c) {
    float v = t[c] + sb[c];
    #pragma unroll
    for (int i = 0; i < EFD; ++i) v += efv[i] * swe[i][c];
    t[c] = fmaxf(v, 0.f);
  }
  float o[4] = {sb2[0], sb2[1], sb2[2], sb2[3]};
  #pragma unroll
  for (int c = 0; c < EH; ++c) {
    #pragma unroll
    for (int j = 0; j < 4; ++j) o[j] += t[c] * sw2[c][j];
  }
  *(float4*)&out[(long long)e * 12 + out_col] = make_float4(o[0], o[1], o[2], o[3]);
  if (copy_ef) *(float4*)&out[(long long)e * 12] = *(const float4*)&copy_ef[e * 4];
}

// ---------------- launch ----------------
extern "C" void kernel_launch(void* const* d_in, const int* in_sizes, int n_in,
                              void* d_out, int out_size, void* d_ws, size_t ws_size,
                              hipStream_t stream) {
  const float* inputs    = (const float*)d_in[0];
  const float* edge_feat = (const float*)d_in[1];
  const float* w_self1   = (const float*)d_in[2];
  const float* w_neigh1  = (const float*)d_in[3];
  const float* b_conv1   = (const float*)d_in[4];
  const float* eu1_wu    = (const float*)d_in[5];
  const float* eu1_wv    = (const float*)d_in[6];
  const float* eu1_we    = (const float*)d_in[7];
  const float* eu1_b     = (const float*)d_in[8];
  const float* eu1_w2    = (const float*)d_in[9];
  const float* eu1_b2    = (const float*)d_in[10];
  const float* w_self2   = (const float*)d_in[11];
  const float* w_neigh2  = (const float*)d_in[12];
  const float* b_conv2   = (const float*)d_in[13];
  const float* eu2_wu    = (const float*)d_in[14];
  const float* eu2_wv    = (const float*)d_in[15];
  const float* eu2_we    = (const float*)d_in[16];
  const float* eu2_b     = (const float*)d_in[17];
  const float* eu2_w2    = (const float*)d_in[18];
  const float* eu2_b2    = (const float*)d_in[19];
  const float* w_self3   = (const float*)d_in[20];
  const float* w_neigh3  = (const float*)d_in[21];
  const float* b_conv3   = (const float*)d_in[22];
  const int*   esrc      = (const int*)d_in[23];
  const int*   edst      = (const int*)d_in[24];

  float* out_h  = (float*)d_out;                           // [N,128]
  float* out_ef = (float*)d_out + (long long)N_NODES * NF; // [E,12]

  // workspace layout (ints first, 16B-aligned float region after)
  int* iws     = (int*)d_ws;
  int* rowptr  = iws;                 // N+1 (pad to 50004)
  int* cursor  = iws + 50004;         // N   (pad to 50004)
  int* cnt     = iws + 100008;        // N   (pad to 50008 -> next at 150016)
  int* btot    = iws + 150016;        // SCAN_NB (pad to 256)
  int* csr_src = iws + 150272;        // E = 800000 -> next at 950272
  float* agg   = (float*)(iws + 950272);       // N*128 (byte off 3801088, %16==0)
  float* hA    = agg + (long long)N_NODES * NF;
  float* hB    = hA + (long long)N_NODES * NF;
  // hu/hv alias agg: agg is dead between k_sage (its last read) and the next
  // layer's k_gather (its next write); k_proj/k_edge run in that window.
  float* hu = agg;
  float* hv = agg + (long long)N_NODES * EH;

  const int N = N_NODES, E = N_EDGES;
  dim3 gsage((N + 63) / 64, 2);
  int gproj = (N + 63) / 64;

  // ---- CSR build (dst-sorted src list), multi-block scan
  k_zeroi<<<(N + 255) / 256, 256, 0, stream>>>(cnt, N);
  k_counti<<<(E + 255) / 256, 256, 0, stream>>>(edst, cnt, E);
  k_bsum<<<SCAN_NB, 256, 0, stream>>>(cnt, btot);
  k_bscan<<<1, 256, 0, stream>>>(btot);
  k_wrow<<<SCAN_NB, 256, 0, stream>>>(cnt, btot, rowptr, cursor);
  k_fill<<<(E + 255) / 256, 256, 0, stream>>>(esrc, edst, cursor, csr_src, E);

  // ---- layer 1
  k_gather<<<N, 128, 0, stream>>>(inputs, rowptr, csr_src, agg);
  k_sage<<<gsage, 256, 0, stream>>>(inputs, agg, w_self1, w_neigh1, b_conv1, hA, N, 1);
  k_proj<<<gproj, 256, 0, stream>>>(hA, eu1_wu, eu1_wv, hu, hv, N);
  k_edge<4><<<(E + 255) / 256, 256, 0, stream>>>(
      hu, hv, esrc, edst, edge_feat, 4, eu1_we, eu1_b, eu1_w2, eu1_b2,
      out_ef, 4, edge_feat, E);

  // ---- layer 2
  k_gather<<<N, 128, 0, stream>>>(hA, rowptr, csr_src, agg);
  k_sage<<<gsage, 256, 0, stream>>>(hA, agg, w_self2, w_neigh2, b_conv2, hB, N, 1);
  k_proj<<<gproj, 256, 0, stream>>>(hB, eu2_wu, eu2_wv, hu, hv, N);
  k_edge<8><<<(E + 255) / 256, 256, 0, stream>>>(
      hu, hv, esrc, edst, out_ef, 12, eu2_we, eu2_b, eu2_w2, eu2_b2,
      out_ef, 8, nullptr, E);

  // ---- layer 3 (no relu, output directly)
  k_gather<<<N, 128, 0, stream>>>(hB, rowptr, csr_src, agg);
  k_sage<<<gsage, 256, 0, stream>>>(hB, agg, w_self3, w_neigh3, b_conv3, out_h, N, 0);
}

// Round 4
// 529.401 us; speedup vs baseline: 3.8898x; 1.2572x over previous
//
#include <hip/hip_runtime.h>

#define N_NODES 50000
#define N_EDGES 800000
#define NF 128   // node feature dim
#define EH 32    // edge hidden
#define SCAN_NB 196  // ceil(50000/256)

typedef __bf16 bf16x8 __attribute__((ext_vector_type(8)));
typedef float f32x4 __attribute__((ext_vector_type(4)));
typedef unsigned short u16x8 __attribute__((ext_vector_type(8)));
typedef unsigned short ushort_t;
typedef unsigned int uint_t;

__device__ inline ushort_t f2bf(float x) {
  uint_t u = __builtin_bit_cast(uint_t, x);
  return (ushort_t)((u + 0x7fffu + ((u >> 16) & 1u)) >> 16);
}
__device__ inline float blo(uint_t u) { return __builtin_bit_cast(float, u << 16); }
__device__ inline float bhi(uint_t u) { return __builtin_bit_cast(float, u & 0xffff0000u); }

// ---------------- CSR build ----------------
__global__ void k_zeroi(int* __restrict__ p, int n) {
  int i = blockIdx.x * blockDim.x + threadIdx.x;
  if (i < n) p[i] = 0;
}

__global__ void k_counti(const int* __restrict__ dst, int* __restrict__ cnt, int E) {
  int e = blockIdx.x * blockDim.x + threadIdx.x;
  if (e < E) atomicAdd(&cnt[dst[e]], 1);
}

__global__ __launch_bounds__(256) void k_bsum(const int* __restrict__ cnt,
                                              int* __restrict__ btot) {
  __shared__ int s[256];
  int t = threadIdx.x;
  int i = blockIdx.x * 256 + t;
  s[t] = (i < N_NODES) ? cnt[i] : 0;
  __syncthreads();
  #pragma unroll
  for (int off = 128; off > 0; off >>= 1) {
    if (t < off) s[t] += s[t + off];
    __syncthreads();
  }
  if (t == 0) btot[blockIdx.x] = s[0];
}

__global__ __launch_bounds__(256) void k_bscan(int* __restrict__ btot) {
  __shared__ int s[256];
  int t = threadIdx.x;
  int v = (t < SCAN_NB) ? btot[t] : 0;
  s[t] = v;
  __syncthreads();
  #pragma unroll
  for (int off = 1; off < 256; off <<= 1) {
    int u = (t >= off) ? s[t - off] : 0;
    __syncthreads();
    s[t] += u;
    __syncthreads();
  }
  if (t < SCAN_NB) btot[t] = s[t] - v;
}

__global__ __launch_bounds__(256) void k_wrow(const int* __restrict__ cnt,
                                              const int* __restrict__ boffs,
                                              int* __restrict__ rowptr,
                                              int* __restrict__ cursor) {
  __shared__ int s[256];
  int t = threadIdx.x;
  int i = blockIdx.x * 256 + t;
  int v = (i < N_NODES) ? cnt[i] : 0;
  s[t] = v;
  __syncthreads();
  #pragma unroll
  for (int off = 1; off < 256; off <<= 1) {
    int u = (t >= off) ? s[t - off] : 0;
    __syncthreads();
    s[t] += u;
    __syncthreads();
  }
  if (i < N_NODES) {
    int ex = boffs[blockIdx.x] + s[t] - v;
    rowptr[i] = ex;
    cursor[i] = ex;
  }
  if (i == 0) rowptr[N_NODES] = N_EDGES;
}

__global__ void k_fill(const int* __restrict__ src, const int* __restrict__ dst,
                       int* __restrict__ cursor, int* __restrict__ csr_src, int E) {
  int e = blockIdx.x * blockDim.x + threadIdx.x;
  if (e < E) {
    int p = atomicAdd(&cursor[dst[e]], 1);
    csr_src[p] = src[e];
  }
}

// ---------------- fp32 -> bf16 cast (node features) ----------------
__global__ void k_cast(const float* __restrict__ x, ushort_t* __restrict__ xb, int n4) {
  int i = blockIdx.x * 256 + threadIdx.x;
  if (i < n4) {
    float4 v = ((const float4*)x)[i];
    uint2 p;
    p.x = (uint_t)f2bf(v.x) | ((uint_t)f2bf(v.y) << 16);
    p.y = (uint_t)f2bf(v.z) | ((uint_t)f2bf(v.w) << 16);
    ((uint2*)xb)[i] = p;
  }
}

// ---------------- weight prep: cast + transpose to k-contiguous bf16 ----------------
// wt_sage[l]: [128][256], wt[n*256+k], k<128 from Ws[k][n], k>=128 from Wn[k-128][n]
// wt_proj[l]: [64][128],  wt[n*128+k], n<32 from Wu[k][n], n>=32 from Wv[k][n-32]
__global__ __launch_bounds__(256) void k_prep(
    const float* __restrict__ ws1, const float* __restrict__ wn1,
    const float* __restrict__ ws2, const float* __restrict__ wn2,
    const float* __restrict__ ws3, const float* __restrict__ wn3,
    const float* __restrict__ wu1, const float* __restrict__ wv1,
    const float* __restrict__ wu2, const float* __restrict__ wv2,
    ushort_t* __restrict__ wt1, ushort_t* __restrict__ wt2, ushort_t* __restrict__ wt3,
    ushort_t* __restrict__ wp1, ushort_t* __restrict__ wp2) {
  int i = blockIdx.x * 256 + threadIdx.x;
  if (i < 98304) {
    int l = i >> 15;
    int j = i & 32767;
    int n = j >> 8, k = j & 255;
    const float* s = (l == 0) ? (k < 128 ? ws1 : wn1)
                   : (l == 1) ? (k < 128 ? ws2 : wn2)
                              : (k < 128 ? ws3 : wn3);
    float v = s[(k & 127) * 128 + n];
    ushort_t* d = (l == 0) ? wt1 : (l == 1) ? wt2 : wt3;
    d[n * 256 + k] = f2bf(v);
  } else if (i < 114688) {
    int j = i - 98304;
    int l = j >> 13;
    int m = j & 8191;
    int n = m >> 7, k = m & 127;
    const float* s = (l == 0) ? (n < 32 ? wu1 : wv1) : (n < 32 ? wu2 : wv2);
    float v = s[k * 32 + (n & 31)];
    ushort_t* d = (l == 0) ? wp1 : wp2;
    d[n * 128 + k] = f2bf(v);
  }
}

// ---------------- CSR mean-gather (bf16 in/out, fp32 accum) ----------------
// one wave per node; lane handles features {2*lane, 2*lane+1} via uint loads
__global__ __launch_bounds__(256) void k_gather_bf(
    const ushort_t* __restrict__ hb, const int* __restrict__ rowptr,
    const int* __restrict__ csr_src, ushort_t* __restrict__ aggb) {
  int n = blockIdx.x * 4 + (threadIdx.x >> 6);
  if (n >= N_NODES) return;
  int lane = threadIdx.x & 63;
  int beg = rowptr[n], end = rowptr[n + 1];
  const uint_t* h32 = (const uint_t*)hb;
  float x0 = 0.f, x1 = 0.f, y0 = 0.f, y1 = 0.f;
  int j = beg;
  for (; j + 4 <= end; j += 4) {
    int s0 = csr_src[j], s1 = csr_src[j + 1], s2 = csr_src[j + 2], s3 = csr_src[j + 3];
    uint_t u0 = h32[s0 * 64 + lane];
    uint_t u1 = h32[s1 * 64 + lane];
    uint_t u2 = h32[s2 * 64 + lane];
    uint_t u3 = h32[s3 * 64 + lane];
    x0 += blo(u0); x1 += bhi(u0);
    y0 += blo(u1); y1 += bhi(u1);
    x0 += blo(u2); x1 += bhi(u2);
    y0 += blo(u3); y1 += bhi(u3);
  }
  for (; j < end; ++j) {
    uint_t u = h32[csr_src[j] * 64 + lane];
    x0 += blo(u); x1 += bhi(u);
  }
  int deg = end - beg;
  float inv = deg > 0 ? 1.0f / (float)deg : 0.f;
  float f0 = (x0 + y0) * inv, f1 = (x1 + y1) * inv;
  ((uint_t*)aggb)[n * 64 + lane] = (uint_t)f2bf(f0) | ((uint_t)f2bf(f1) << 16);
}

// ---------------- SAGE via MFMA: out = act([h|agg] @ [Ws;Wn] + b) ----------------
// Block 256 = 4 waves. Block tile 64(M)x128(N); wave w -> cols [32w,32w+32), all 64 rows.
// A-frag: lane holds A[m=lane&15][k=quad*8+j]; B-frag: B[k=quad*8+j][n=lane&15];
// C/D: row=quad*4+reg, col=lane&15  (verified m89/m91/m120 layouts).
__global__ __launch_bounds__(256) void k_sage_mfma(
    const ushort_t* __restrict__ xb, const ushort_t* __restrict__ ab,
    const ushort_t* __restrict__ wt,  // [128][256] bf16, wt[n*256+k]
    const float* __restrict__ bias,
    ushort_t* __restrict__ out_bf, float* __restrict__ out_f32,
    int M, int do_relu) {
  int tid = threadIdx.x;
  int wave = tid >> 6, lane = tid & 63;
  int l16 = lane & 15, quad = lane >> 4;
  int row0 = blockIdx.x * 64;
  int n0 = wave * 32;
  f32x4 acc[4][2];
  #pragma unroll
  for (int a = 0; a < 4; ++a)
    #pragma unroll
    for (int b = 0; b < 2; ++b) acc[a][b] = (f32x4){0.f, 0.f, 0.f, 0.f};

  #pragma unroll
  for (int ks = 0; ks < 8; ++ks) {
    int k0 = ks * 32;
    const ushort_t* A = (ks < 4) ? xb : ab;
    int ka = (k0 & 127) + quad * 8;
    bf16x8 afr[4];
    #pragma unroll
    for (int mt = 0; mt < 4; ++mt) {
      int r = row0 + mt * 16 + l16;
      if (r >= M) r = M - 1;
      afr[mt] = __builtin_bit_cast(bf16x8, *(const u16x8*)&A[r * NF + ka]);
    }
    bf16x8 bfr[2];
    #pragma unroll
    for (int nt = 0; nt < 2; ++nt) {
      int n = n0 + nt * 16 + l16;
      bfr[nt] = __builtin_bit_cast(bf16x8, *(const u16x8*)&wt[n * 256 + k0 + quad * 8]);
    }
    #pragma unroll
    for (int mt = 0; mt < 4; ++mt)
      #pragma unroll
      for (int nt = 0; nt < 2; ++nt)
        acc[mt][nt] = __builtin_amdgcn_mfma_f32_16x16x32_bf16(
            afr[mt], bfr[nt], acc[mt][nt], 0, 0, 0);
  }

  #pragma unroll
  for (int nt = 0; nt < 2; ++nt) {
    int col = n0 + nt * 16 + l16;
    float bv = bias[col];
    #pragma unroll
    for (int mt = 0; mt < 4; ++mt) {
      #pragma unroll
      for (int reg = 0; reg < 4; ++reg) {
        int r = row0 + mt * 16 + quad * 4 + reg;
        if (r < M) {
          float v = acc[mt][nt][reg] + bv;
          if (do_relu) v = fmaxf(v, 0.f);
          if (out_f32) out_f32[r * NF + col] = v;
          else         out_bf[r * NF + col] = f2bf(v);
        }
      }
    }
  }
}

// ---------------- edge projections via MFMA: [hu|hv] = h @ [Wu|Wv] ----------------
// Block 256 = 4 waves; wave w -> 16-col tile w of the 64-wide output; 64 rows.
__global__ __launch_bounds__(256) void k_proj_mfma(
    const ushort_t* __restrict__ hb, const ushort_t* __restrict__ wp,  // [64][128]
    ushort_t* __restrict__ hub, ushort_t* __restrict__ hvb, int M) {
  int tid = threadIdx.x;
  int wave = tid >> 6, lane = tid & 63;
  int l16 = lane & 15, quad = lane >> 4;
  int row0 = blockIdx.x * 64;
  int nb = wave * 16;
  f32x4 acc[4];
  #pragma unroll
  for (int a = 0; a < 4; ++a) acc[a] = (f32x4){0.f, 0.f, 0.f, 0.f};

  #pragma unroll
  for (int ks = 0; ks < 4; ++ks) {
    int k0 = ks * 32;
    bf16x8 afr[4];
    #pragma unroll
    for (int mt = 0; mt < 4; ++mt) {
      int r = row0 + mt * 16 + l16;
      if (r >= M) r = M - 1;
      afr[mt] = __builtin_bit_cast(bf16x8, *(const u16x8*)&hb[r * NF + k0 + quad * 8]);
    }
    bf16x8 bfr = __builtin_bit_cast(bf16x8, *(const u16x8*)&wp[(nb + l16) * NF + k0 + quad * 8]);
    #pragma unroll
    for (int mt = 0; mt < 4; ++mt)
      acc[mt] = __builtin_amdgcn_mfma_f32_16x16x32_bf16(afr[mt], bfr, acc[mt], 0, 0, 0);
  }

  int col = nb + l16;
  #pragma unroll
  for (int mt = 0; mt < 4; ++mt) {
    #pragma unroll
    for (int reg = 0; reg < 4; ++reg) {
      int r = row0 + mt * 16 + quad * 4 + reg;
      if (r < M) {
        ushort_t v = f2bf(acc[mt][reg]);
        if (col < 32) hub[r * EH + col] = v;
        else          hvb[r * EH + col - 32] = v;
      }
    }
  }
}

// ---------------- edge MLP: out4 = relu(hu[src]+hv[dst]+ef@We+b)@W2 + b2 ----------------
template <int EFD>
__global__ __launch_bounds__(256) void k_edge(
    const ushort_t* __restrict__ hub, const ushort_t* __restrict__ hvb,
    const int* __restrict__ src, const int* __restrict__ dst,
    const float* __restrict__ ef, int ef_stride,
    const float* __restrict__ we, const float* __restrict__ b,
    const float* __restrict__ w2, const float* __restrict__ b2,
    float* __restrict__ out, int out_col,
    const float* __restrict__ copy_ef, int E) {
  __shared__ float swe[EFD][EH];
  __shared__ float sw2[EH][4];
  __shared__ float sb[EH];
  __shared__ float sb2[4];
  int tid = threadIdx.x;
  for (int i = tid; i < EFD * EH; i += 256) swe[i >> 5][i & 31] = we[i];
  if (tid < EH * 4) sw2[tid >> 2][tid & 3] = w2[tid];
  if (tid < EH) sb[tid] = b[tid];
  if (tid < 4) sb2[tid] = b2[tid];
  __syncthreads();
  int e = blockIdx.x * 256 + tid;
  if (e >= E) return;
  int s = src[e], d = dst[e];
  const uint4* pu = (const uint4*)&hub[(long long)s * EH];
  const uint4* pv = (const uint4*)&hvb[(long long)d * EH];
  float efv[EFD];
  #pragma unroll
  for (int i = 0; i < EFD; ++i) efv[i] = ef[(long long)e * ef_stride + i];
  float t[EH];
  #pragma unroll
  for (int q = 0; q < 4; ++q) {  // 4 x uint4 = 32 bf16
    uint4 au = pu[q];
    uint4 av = pv[q];
    t[q * 8 + 0] = blo(au.x) + blo(av.x);
    t[q * 8 + 1] = bhi(au.x) + bhi(av.x);
    t[q * 8 + 2] = blo(au.y) + blo(av.y);
    t[q * 8 + 3] = bhi(au.y) + bhi(av.y);
    t[q * 8 + 4] = blo(au.z) + blo(av.z);
    t[q * 8 + 5] = bhi(au.z) + bhi(av.z);
    t[q * 8 + 6] = blo(au.w) + blo(av.w);
    t[q * 8 + 7] = bhi(au.w) + bhi(av.w);
  }
  #pragma unroll
  for (int c = 0; c < EH; ++c) {
    float v = t[c] + sb[c];
    #pragma unroll
    for (int i = 0; i < EFD; ++i) v += efv[i] * swe[i][c];
    t[c] = fmaxf(v, 0.f);
  }
  float o[4] = {sb2[0], sb2[1], sb2[2], sb2[3]};
  #pragma unroll
  for (int c = 0; c < EH; ++c) {
    #pragma unroll
    for (int j = 0; j < 4; ++j) o[j] += t[c] * sw2[c][j];
  }
  *(float4*)&out[(long long)e * 12 + out_col] = make_float4(o[0], o[1], o[2], o[3]);
  if (copy_ef) *(float4*)&out[(long long)e * 12] = *(const float4*)&copy_ef[e * 4];
}

// ---------------- launch ----------------
extern "C" void kernel_launch(void* const* d_in, const int* in_sizes, int n_in,
                              void* d_out, int out_size, void* d_ws, size_t ws_size,
                              hipStream_t stream) {
  const float* inputs    = (const float*)d_in[0];
  const float* edge_feat = (const float*)d_in[1];
  const float* w_self1   = (const float*)d_in[2];
  const float* w_neigh1  = (const float*)d_in[3];
  const float* b_conv1   = (const float*)d_in[4];
  const float* eu1_wu    = (const float*)d_in[5];
  const float* eu1_wv    = (const float*)d_in[6];
  const float* eu1_we    = (const float*)d_in[7];
  const float* eu1_b     = (const float*)d_in[8];
  const float* eu1_w2    = (const float*)d_in[9];
  const float* eu1_b2    = (const float*)d_in[10];
  const float* w_self2   = (const float*)d_in[11];
  const float* w_neigh2  = (const float*)d_in[12];
  const float* b_conv2   = (const float*)d_in[13];
  const float* eu2_wu    = (const float*)d_in[14];
  const float* eu2_wv    = (const float*)d_in[15];
  const float* eu2_we    = (const float*)d_in[16];
  const float* eu2_b     = (const float*)d_in[17];
  const float* eu2_w2    = (const float*)d_in[18];
  const float* eu2_b2    = (const float*)d_in[19];
  const float* w_self3   = (const float*)d_in[20];
  const float* w_neigh3  = (const float*)d_in[21];
  const float* b_conv3   = (const float*)d_in[22];
  const int*   esrc      = (const int*)d_in[23];
  const int*   edst      = (const int*)d_in[24];

  float* out_h  = (float*)d_out;                           // [N,128]
  float* out_ef = (float*)d_out + (long long)N_NODES * NF; // [E,12]

  // workspace: ints, then bf16 region
  int* iws     = (int*)d_ws;
  int* rowptr  = iws;                 // N+1
  int* cursor  = iws + 50004;
  int* cnt     = iws + 100008;
  int* btot    = iws + 150016;        // 256
  int* csr_src = iws + 150272;        // 800000 -> ends 950272
  ushort_t* ub = (ushort_t*)(iws + 950272);   // byte off 3801088, 16B aligned
  ushort_t* xb   = ub;                        // N*128
  ushort_t* hAb  = ub + 6400000;
  ushort_t* hBb  = ub + 12800000;
  ushort_t* aggb = ub + 19200000;
  ushort_t* wt1  = ub + 25600000;             // 32768 each
  ushort_t* wt2  = ub + 25632768;
  ushort_t* wt3  = ub + 25665536;
  ushort_t* wp1  = ub + 25698304;             // 8192 each
  ushort_t* wp2  = ub + 25706496;
  // hu/hv alias aggb (dead between k_sage read and next layer's gather write)
  ushort_t* hub = aggb;
  ushort_t* hvb = aggb + (long long)N_NODES * EH;

  const int N = N_NODES, E = N_EDGES;
  int gsage = (N + 63) / 64;  // 782

  // ---- CSR build + weight prep + input cast
  k_zeroi<<<(N + 255) / 256, 256, 0, stream>>>(cnt, N);
  k_counti<<<(E + 255) / 256, 256, 0, stream>>>(edst, cnt, E);
  k_bsum<<<SCAN_NB, 256, 0, stream>>>(cnt, btot);
  k_bscan<<<1, 256, 0, stream>>>(btot);
  k_wrow<<<SCAN_NB, 256, 0, stream>>>(cnt, btot, rowptr, cursor);
  k_fill<<<(E + 255) / 256, 256, 0, stream>>>(esrc, edst, cursor, csr_src, E);
  k_prep<<<448, 256, 0, stream>>>(w_self1, w_neigh1, w_self2, w_neigh2, w_self3, w_neigh3,
                                  eu1_wu, eu1_wv, eu2_wu, eu2_wv,
                                  wt1, wt2, wt3, wp1, wp2);
  k_cast<<<(N * NF / 4 + 255) / 256, 256, 0, stream>>>(inputs, xb, N * NF / 4);

  // ---- layer 1
  k_gather_bf<<<(N + 3) / 4, 256, 0, stream>>>(xb, rowptr, csr_src, aggb);
  k_sage_mfma<<<gsage, 256, 0, stream>>>(xb, aggb, wt1, b_conv1, hAb, nullptr, N, 1);
  k_proj_mfma<<<gsage, 256, 0, stream>>>(hAb, wp1, hub, hvb, N);
  k_edge<4><<<(E + 255) / 256, 256, 0, stream>>>(
      hub, hvb, esrc, edst, edge_feat, 4, eu1_we, eu1_b, eu1_w2, eu1_b2,
      out_ef, 4, edge_feat, E);

  // ---- layer 2
  k_gather_bf<<<(N + 3) / 4, 256, 0, stream>>>(hAb, rowptr, csr_src, aggb);
  k_sage_mfma<<<gsage, 256, 0, stream>>>(hAb, aggb, wt2, b_conv2, hBb, nullptr, N, 1);
  k_proj_mfma<<<gsage, 256, 0, stream>>>(hBb, wp2, hub, hvb, N);
  k_edge<8><<<(E + 255) / 256, 256, 0, stream>>>(
      hub, hvb, esrc, edst, out_ef, 12, eu2_we, eu2_b, eu2_w2, eu2_b2,
      out_ef, 8, nullptr, E);

  // ---- layer 3 (no relu, fp32 output)
  k_gather_bf<<<(N + 3) / 4, 256, 0, stream>>>(hBb, rowptr, csr_src, aggb);
  k_sage_mfma<<<gsage, 256, 0, stream>>>(hBb, aggb, wt3, b_conv3, nullptr, out_h, N, 0);
}

// Round 5
// 518.958 us; speedup vs baseline: 3.9681x; 1.0201x over previous
//
#include <hip/hip_runtime.h>

#define N_NODES 50000
#define N_EDGES 800000
#define NF 128   // node feature dim
#define EH 32    // edge hidden
#define SCAN_NB 196  // ceil(50000/256)

typedef __bf16 bf16x8 __attribute__((ext_vector_type(8)));
typedef float f32x4 __attribute__((ext_vector_type(4)));
typedef unsigned short u16x8 __attribute__((ext_vector_type(8)));
typedef unsigned short ushort_t;
typedef unsigned int uint_t;

__device__ inline ushort_t f2bf(float x) {
  uint_t u = __builtin_bit_cast(uint_t, x);
  return (ushort_t)((u + 0x7fffu + ((u >> 16) & 1u)) >> 16);
}
__device__ inline float blo(uint_t u) { return __builtin_bit_cast(float, u << 16); }
__device__ inline float bhi(uint_t u) { return __builtin_bit_cast(float, u & 0xffff0000u); }

// ---------------- CSR build ----------------
__global__ void k_zeroi(int* __restrict__ p, int n) {
  int i = blockIdx.x * blockDim.x + threadIdx.x;
  if (i < n) p[i] = 0;
}

__global__ void k_counti(const int* __restrict__ dst, int* __restrict__ cnt, int E) {
  int e = blockIdx.x * blockDim.x + threadIdx.x;
  if (e < E) atomicAdd(&cnt[dst[e]], 1);
}

__global__ __launch_bounds__(256) void k_bsum(const int* __restrict__ cnt,
                                              int* __restrict__ btot) {
  __shared__ int s[256];
  int t = threadIdx.x;
  int i = blockIdx.x * 256 + t;
  s[t] = (i < N_NODES) ? cnt[i] : 0;
  __syncthreads();
  #pragma unroll
  for (int off = 128; off > 0; off >>= 1) {
    if (t < off) s[t] += s[t + off];
    __syncthreads();
  }
  if (t == 0) btot[blockIdx.x] = s[0];
}

__global__ __launch_bounds__(256) void k_bscan(int* __restrict__ btot) {
  __shared__ int s[256];
  int t = threadIdx.x;
  int v = (t < SCAN_NB) ? btot[t] : 0;
  s[t] = v;
  __syncthreads();
  #pragma unroll
  for (int off = 1; off < 256; off <<= 1) {
    int u = (t >= off) ? s[t - off] : 0;
    __syncthreads();
    s[t] += u;
    __syncthreads();
  }
  if (t < SCAN_NB) btot[t] = s[t] - v;
}

__global__ __launch_bounds__(256) void k_wrow(const int* __restrict__ cnt,
                                              const int* __restrict__ boffs,
                                              int* __restrict__ rowptr,
                                              int* __restrict__ cursor) {
  __shared__ int s[256];
  int t = threadIdx.x;
  int i = blockIdx.x * 256 + t;
  int v = (i < N_NODES) ? cnt[i] : 0;
  s[t] = v;
  __syncthreads();
  #pragma unroll
  for (int off = 1; off < 256; off <<= 1) {
    int u = (t >= off) ? s[t - off] : 0;
    __syncthreads();
    s[t] += u;
    __syncthreads();
  }
  if (i < N_NODES) {
    int ex = boffs[blockIdx.x] + s[t] - v;
    rowptr[i] = ex;
    cursor[i] = ex;
  }
  if (i == 0) rowptr[N_NODES] = N_EDGES;
}

__global__ void k_fill(const int* __restrict__ src, const int* __restrict__ dst,
                       int* __restrict__ cursor, int* __restrict__ csr_src, int E) {
  int e = blockIdx.x * blockDim.x + threadIdx.x;
  if (e < E) {
    int p = atomicAdd(&cursor[dst[e]], 1);
    csr_src[p] = src[e];
  }
}

// ---------------- fp32 -> bf16 cast ----------------
__global__ void k_cast(const float* __restrict__ x, ushort_t* __restrict__ xb, int n4) {
  int i = blockIdx.x * 256 + threadIdx.x;
  if (i < n4) {
    float4 v = ((const float4*)x)[i];
    uint2 p;
    p.x = (uint_t)f2bf(v.x) | ((uint_t)f2bf(v.y) << 16);
    p.y = (uint_t)f2bf(v.z) | ((uint_t)f2bf(v.w) << 16);
    ((uint2*)xb)[i] = p;
  }
}

// ---------------- weight prep (cast + transpose, k-contiguous bf16) ----------------
__global__ __launch_bounds__(256) void k_prep(
    const float* __restrict__ ws1, const float* __restrict__ wn1,
    const float* __restrict__ ws2, const float* __restrict__ wn2,
    const float* __restrict__ ws3, const float* __restrict__ wn3,
    const float* __restrict__ wu1, const float* __restrict__ wv1,
    const float* __restrict__ wu2, const float* __restrict__ wv2,
    ushort_t* __restrict__ wt1, ushort_t* __restrict__ wt2, ushort_t* __restrict__ wt3,
    ushort_t* __restrict__ wp1, ushort_t* __restrict__ wp2) {
  int i = blockIdx.x * 256 + threadIdx.x;
  if (i < 98304) {
    int l = i >> 15;
    int j = i & 32767;
    int n = j >> 8, k = j & 255;
    const float* s = (l == 0) ? (k < 128 ? ws1 : wn1)
                   : (l == 1) ? (k < 128 ? ws2 : wn2)
                              : (k < 128 ? ws3 : wn3);
    float v = s[(k & 127) * 128 + n];
    ushort_t* d = (l == 0) ? wt1 : (l == 1) ? wt2 : wt3;
    d[n * 256 + k] = f2bf(v);
  } else if (i < 114688) {
    int j = i - 98304;
    int l = j >> 13;
    int m = j & 8191;
    int n = m >> 7, k = m & 127;
    const float* s = (l == 0) ? (n < 32 ? wu1 : wv1) : (n < 32 ? wu2 : wv2);
    float v = s[k * 32 + (n & 31)];
    ushort_t* d = (l == 0) ? wp1 : wp2;
    d[n * 128 + k] = f2bf(v);
  }
}

// ---------------- CSR mean-gather: half-wave per neighbor row ----------------
// wave per node; lanes 0-31 even neighbors, 32-63 odd; uint2 (4 bf16) per lane.
__global__ __launch_bounds__(256) void k_gather_bf(
    const ushort_t* __restrict__ hb, const int* __restrict__ rowptr,
    const int* __restrict__ csr_src, ushort_t* __restrict__ aggb) {
  int n = blockIdx.x * 4 + (threadIdx.x >> 6);
  if (n >= N_NODES) return;
  int lane = threadIdx.x & 63;
  int half = lane >> 5;
  int l32 = lane & 31;
  int beg = rowptr[n], end = rowptr[n + 1];
  float f0 = 0.f, f1 = 0.f, f2 = 0.f, f3 = 0.f;
  int j = beg;
  for (; j + 8 <= end; j += 8) {
    int sa = csr_src[j + half];
    int sb_ = csr_src[j + 2 + half];
    int sc = csr_src[j + 4 + half];
    int sd = csr_src[j + 6 + half];
    uint2 ua = *(const uint2*)&hb[sa * NF + l32 * 4];
    uint2 ub_ = *(const uint2*)&hb[sb_ * NF + l32 * 4];
    uint2 uc = *(const uint2*)&hb[sc * NF + l32 * 4];
    uint2 ud = *(const uint2*)&hb[sd * NF + l32 * 4];
    f0 += blo(ua.x) + blo(ub_.x) + blo(uc.x) + blo(ud.x);
    f1 += bhi(ua.x) + bhi(ub_.x) + bhi(uc.x) + bhi(ud.x);
    f2 += blo(ua.y) + blo(ub_.y) + blo(uc.y) + blo(ud.y);
    f3 += bhi(ua.y) + bhi(ub_.y) + bhi(uc.y) + bhi(ud.y);
  }
  for (; j + 2 <= end; j += 2) {
    int sa = csr_src[j + half];
    uint2 ua = *(const uint2*)&hb[sa * NF + l32 * 4];
    f0 += blo(ua.x); f1 += bhi(ua.x); f2 += blo(ua.y); f3 += bhi(ua.y);
  }
  if (j < end && half == 0) {
    int sa = csr_src[j];
    uint2 ua = *(const uint2*)&hb[sa * NF + l32 * 4];
    f0 += blo(ua.x); f1 += bhi(ua.x); f2 += blo(ua.y); f3 += bhi(ua.y);
  }
  f0 += __shfl_down(f0, 32, 64);
  f1 += __shfl_down(f1, 32, 64);
  f2 += __shfl_down(f2, 32, 64);
  f3 += __shfl_down(f3, 32, 64);
  if (half == 0) {
    int deg = end - beg;
    float inv = deg > 0 ? 1.0f / (float)deg : 0.f;
    uint2 p;
    p.x = (uint_t)f2bf(f0 * inv) | ((uint_t)f2bf(f1 * inv) << 16);
    p.y = (uint_t)f2bf(f2 * inv) | ((uint_t)f2bf(f3 * inv) << 16);
    *(uint2*)&aggb[n * NF + l32 * 4] = p;
  }
}

// ---------------- SAGE via MFMA (unchanged) ----------------
__global__ __launch_bounds__(256) void k_sage_mfma(
    const ushort_t* __restrict__ xb, const ushort_t* __restrict__ ab,
    const ushort_t* __restrict__ wt,  // [128][256] bf16, wt[n*256+k]
    const float* __restrict__ bias,
    ushort_t* __restrict__ out_bf, float* __restrict__ out_f32,
    int M, int do_relu) {
  int tid = threadIdx.x;
  int wave = tid >> 6, lane = tid & 63;
  int l16 = lane & 15, quad = lane >> 4;
  int row0 = blockIdx.x * 64;
  int n0 = wave * 32;
  f32x4 acc[4][2];
  #pragma unroll
  for (int a = 0; a < 4; ++a)
    #pragma unroll
    for (int b = 0; b < 2; ++b) acc[a][b] = (f32x4){0.f, 0.f, 0.f, 0.f};

  #pragma unroll
  for (int ks = 0; ks < 8; ++ks) {
    int k0 = ks * 32;
    const ushort_t* A = (ks < 4) ? xb : ab;
    int ka = (k0 & 127) + quad * 8;
    bf16x8 afr[4];
    #pragma unroll
    for (int mt = 0; mt < 4; ++mt) {
      int r = row0 + mt * 16 + l16;
      if (r >= M) r = M - 1;
      afr[mt] = __builtin_bit_cast(bf16x8, *(const u16x8*)&A[r * NF + ka]);
    }
    bf16x8 bfr[2];
    #pragma unroll
    for (int nt = 0; nt < 2; ++nt) {
      int n = n0 + nt * 16 + l16;
      bfr[nt] = __builtin_bit_cast(bf16x8, *(const u16x8*)&wt[n * 256 + k0 + quad * 8]);
    }
    #pragma unroll
    for (int mt = 0; mt < 4; ++mt)
      #pragma unroll
      for (int nt = 0; nt < 2; ++nt)
        acc[mt][nt] = __builtin_amdgcn_mfma_f32_16x16x32_bf16(
            afr[mt], bfr[nt], acc[mt][nt], 0, 0, 0);
  }

  #pragma unroll
  for (int nt = 0; nt < 2; ++nt) {
    int col = n0 + nt * 16 + l16;
    float bv = bias[col];
    #pragma unroll
    for (int mt = 0; mt < 4; ++mt) {
      #pragma unroll
      for (int reg = 0; reg < 4; ++reg) {
        int r = row0 + mt * 16 + quad * 4 + reg;
        if (r < M) {
          float v = acc[mt][nt][reg] + bv;
          if (do_relu) v = fmaxf(v, 0.f);
          if (out_f32) out_f32[r * NF + col] = v;
          else         out_bf[r * NF + col] = f2bf(v);
        }
      }
    }
  }
}

// ---------------- edge projections via MFMA (unchanged) ----------------
__global__ __launch_bounds__(256) void k_proj_mfma(
    const ushort_t* __restrict__ hb, const ushort_t* __restrict__ wp,  // [64][128]
    ushort_t* __restrict__ hub, ushort_t* __restrict__ hvb, int M) {
  int tid = threadIdx.x;
  int wave = tid >> 6, lane = tid & 63;
  int l16 = lane & 15, quad = lane >> 4;
  int row0 = blockIdx.x * 64;
  int nb = wave * 16;
  f32x4 acc[4];
  #pragma unroll
  for (int a = 0; a < 4; ++a) acc[a] = (f32x4){0.f, 0.f, 0.f, 0.f};

  #pragma unroll
  for (int ks = 0; ks < 4; ++ks) {
    int k0 = ks * 32;
    bf16x8 afr[4];
    #pragma unroll
    for (int mt = 0; mt < 4; ++mt) {
      int r = row0 + mt * 16 + l16;
      if (r >= M) r = M - 1;
      afr[mt] = __builtin_bit_cast(bf16x8, *(const u16x8*)&hb[r * NF + k0 + quad * 8]);
    }
    bf16x8 bfr = __builtin_bit_cast(bf16x8, *(const u16x8*)&wp[(nb + l16) * NF + k0 + quad * 8]);
    #pragma unroll
    for (int mt = 0; mt < 4; ++mt)
      acc[mt] = __builtin_amdgcn_mfma_f32_16x16x32_bf16(afr[mt], bfr, acc[mt], 0, 0, 0);
  }

  int col = nb + l16;
  #pragma unroll
  for (int mt = 0; mt < 4; ++mt) {
    #pragma unroll
    for (int reg = 0; reg < 4; ++reg) {
      int r = row0 + mt * 16 + quad * 4 + reg;
      if (r < M) {
        ushort_t v = f2bf(acc[mt][reg]);
        if (col < 32) hub[r * EH + col] = v;
        else          hvb[r * EH + col - 32] = v;
      }
    }
  }
}

// ---------------- edge MLP, cooperative: 8 lanes per edge ----------------
// lane q of an edge handles channels [4q,4q+4); hu/hv rows loaded as uint2/lane
// (contiguous 64 B per edge); outputs combined via 3 xor-shuffles.
template <int EFD>
__global__ __launch_bounds__(256) void k_edge(
    const ushort_t* __restrict__ hub, const ushort_t* __restrict__ hvb,
    const int* __restrict__ src, const int* __restrict__ dst,
    const float* __restrict__ ef, int ef_stride,
    const float* __restrict__ we, const float* __restrict__ b,
    const float* __restrict__ w2, const float* __restrict__ b2,
    float* __restrict__ out, int out_col,
    const float* __restrict__ copy_ef, int E) {
  __shared__ float swe[EFD][EH];
  __shared__ float sw2[EH][4];
  __shared__ float sb[EH];
  __shared__ float sb2v[4];
  int tid = threadIdx.x;
  for (int i = tid; i < EFD * EH; i += 256) swe[i >> 5][i & 31] = we[i];
  if (tid < EH * 4) sw2[tid >> 2][tid & 3] = w2[tid];
  if (tid < EH) sb[tid] = b[tid];
  if (tid < 4) sb2v[tid] = b2[tid];
  __syncthreads();
  int gi = blockIdx.x * 256 + tid;
  int e = gi >> 3;
  int q = gi & 7;
  if (e >= E) return;
  int s = src[e], d = dst[e];
  int cb = q * 4;
  uint2 au = *(const uint2*)&hub[s * EH + cb];
  uint2 av = *(const uint2*)&hvb[d * EH + cb];
  float efv[EFD];
  {
    float4 v = *(const float4*)&ef[(long long)e * ef_stride];
    efv[0] = v.x; efv[1] = v.y; efv[2] = v.z; efv[3] = v.w;
    if (EFD == 8) {
      float4 v1 = *(const float4*)&ef[(long long)e * ef_stride + 4];
      efv[4] = v1.x; efv[5] = v1.y; efv[6] = v1.z; efv[7] = v1.w;
    }
  }
  float t0 = blo(au.x) + blo(av.x) + sb[cb + 0];
  float t1 = bhi(au.x) + bhi(av.x) + sb[cb + 1];
  float t2 = blo(au.y) + blo(av.y) + sb[cb + 2];
  float t3 = bhi(au.y) + bhi(av.y) + sb[cb + 3];
  #pragma unroll
  for (int i = 0; i < EFD; ++i) {
    float efi = efv[i];
    t0 += efi * swe[i][cb + 0];
    t1 += efi * swe[i][cb + 1];
    t2 += efi * swe[i][cb + 2];
    t3 += efi * swe[i][cb + 3];
  }
  t0 = fmaxf(t0, 0.f); t1 = fmaxf(t1, 0.f);
  t2 = fmaxf(t2, 0.f); t3 = fmaxf(t3, 0.f);
  float o0 = t0 * sw2[cb + 0][0] + t1 * sw2[cb + 1][0] + t2 * sw2[cb + 2][0] + t3 * sw2[cb + 3][0];
  float o1 = t0 * sw2[cb + 0][1] + t1 * sw2[cb + 1][1] + t2 * sw2[cb + 2][1] + t3 * sw2[cb + 3][1];
  float o2 = t0 * sw2[cb + 0][2] + t1 * sw2[cb + 1][2] + t2 * sw2[cb + 2][2] + t3 * sw2[cb + 3][2];
  float o3 = t0 * sw2[cb + 0][3] + t1 * sw2[cb + 1][3] + t2 * sw2[cb + 2][3] + t3 * sw2[cb + 3][3];
  #pragma unroll
  for (int m = 4; m; m >>= 1) {
    o0 += __shfl_xor(o0, m, 64);
    o1 += __shfl_xor(o1, m, 64);
    o2 += __shfl_xor(o2, m, 64);
    o3 += __shfl_xor(o3, m, 64);
  }
  if (q == 0) {
    *(float4*)&out[(long long)e * 12 + out_col] =
        make_float4(o0 + sb2v[0], o1 + sb2v[1], o2 + sb2v[2], o3 + sb2v[3]);
  }
  if (copy_ef && q == 1) {
    *(float4*)&out[(long long)e * 12] = *(const float4*)&copy_ef[e * 4];
  }
}

// ---------------- launch ----------------
extern "C" void kernel_launch(void* const* d_in, const int* in_sizes, int n_in,
                              void* d_out, int out_size, void* d_ws, size_t ws_size,
                              hipStream_t stream) {
  const float* inputs    = (const float*)d_in[0];
  const float* edge_feat = (const float*)d_in[1];
  const float* w_self1   = (const float*)d_in[2];
  const float* w_neigh1  = (const float*)d_in[3];
  const float* b_conv1   = (const float*)d_in[4];
  const float* eu1_wu    = (const float*)d_in[5];
  const float* eu1_wv    = (const float*)d_in[6];
  const float* eu1_we    = (const float*)d_in[7];
  const float* eu1_b     = (const float*)d_in[8];
  const float* eu1_w2    = (const float*)d_in[9];
  const float* eu1_b2    = (const float*)d_in[10];
  const float* w_self2   = (const float*)d_in[11];
  const float* w_neigh2  = (const float*)d_in[12];
  const float* b_conv2   = (const float*)d_in[13];
  const float* eu2_wu    = (const float*)d_in[14];
  const float* eu2_wv    = (const float*)d_in[15];
  const float* eu2_we    = (const float*)d_in[16];
  const float* eu2_b     = (const float*)d_in[17];
  const float* eu2_w2    = (const float*)d_in[18];
  const float* eu2_b2    = (const float*)d_in[19];
  const float* w_self3   = (const float*)d_in[20];
  const float* w_neigh3  = (const float*)d_in[21];
  const float* b_conv3   = (const float*)d_in[22];
  const int*   esrc      = (const int*)d_in[23];
  const int*   edst      = (const int*)d_in[24];

  float* out_h  = (float*)d_out;                           // [N,128]
  float* out_ef = (float*)d_out + (long long)N_NODES * NF; // [E,12]

  // workspace: ints, then bf16 region
  int* iws     = (int*)d_ws;
  int* rowptr  = iws;                 // N+1
  int* cursor  = iws + 50004;
  int* cnt     = iws + 100008;
  int* btot    = iws + 150016;        // 256
  int* csr_src = iws + 150272;        // 800000 -> ends 950272
  ushort_t* ub = (ushort_t*)(iws + 950272);   // byte off 3801088, 16B aligned
  ushort_t* xb   = ub;                        // N*128
  ushort_t* hAb  = ub + 6400000;
  ushort_t* hBb  = ub + 12800000;
  ushort_t* aggb = ub + 19200000;
  ushort_t* wt1  = ub + 25600000;             // 32768 each
  ushort_t* wt2  = ub + 25632768;
  ushort_t* wt3  = ub + 25665536;
  ushort_t* wp1  = ub + 25698304;             // 8192 each
  ushort_t* wp2  = ub + 25706496;
  // hu/hv alias aggb (dead between k_sage read and next layer's gather write)
  ushort_t* hub = aggb;
  ushort_t* hvb = aggb + (long long)N_NODES * EH;

  const int N = N_NODES, E = N_EDGES;
  int gsage = (N + 63) / 64;  // 782
  int gedge = (E * 8) / 256;  // 25000 exactly

  // ---- CSR build + weight prep + input cast
  k_zeroi<<<(N + 255) / 256, 256, 0, stream>>>(cnt, N);
  k_counti<<<(E + 255) / 256, 256, 0, stream>>>(edst, cnt, E);
  k_bsum<<<SCAN_NB, 256, 0, stream>>>(cnt, btot);
  k_bscan<<<1, 256, 0, stream>>>(btot);
  k_wrow<<<SCAN_NB, 256, 0, stream>>>(cnt, btot, rowptr, cursor);
  k_fill<<<(E + 255) / 256, 256, 0, stream>>>(esrc, edst, cursor, csr_src, E);
  k_prep<<<448, 256, 0, stream>>>(w_self1, w_neigh1, w_self2, w_neigh2, w_self3, w_neigh3,
                                  eu1_wu, eu1_wv, eu2_wu, eu2_wv,
                                  wt1, wt2, wt3, wp1, wp2);
  k_cast<<<(N * NF / 4 + 255) / 256, 256, 0, stream>>>(inputs, xb, N * NF / 4);

  // ---- layer 1
  k_gather_bf<<<(N + 3) / 4, 256, 0, stream>>>(xb, rowptr, csr_src, aggb);
  k_sage_mfma<<<gsage, 256, 0, stream>>>(xb, aggb, wt1, b_conv1, hAb, nullptr, N, 1);
  k_proj_mfma<<<gsage, 256, 0, stream>>>(hAb, wp1, hub, hvb, N);
  k_edge<4><<<gedge, 256, 0, stream>>>(
      hub, hvb, esrc, edst, edge_feat, 4, eu1_we, eu1_b, eu1_w2, eu1_b2,
      out_ef, 4, edge_feat, E);

  // ---- layer 2
  k_gather_bf<<<(N + 3) / 4, 256, 0, stream>>>(hAb, rowptr, csr_src, aggb);
  k_sage_mfma<<<gsage, 256, 0, stream>>>(hAb, aggb, wt2, b_conv2, hBb, nullptr, N, 1);
  k_proj_mfma<<<gsage, 256, 0, stream>>>(hBb, wp2, hub, hvb, N);
  k_edge<8><<<gedge, 256, 0, stream>>>(
      hub, hvb, esrc, edst, out_ef, 12, eu2_we, eu2_b, eu2_w2, eu2_b2,
      out_ef, 8, nullptr, E);

  // ---- layer 3 (no relu, fp32 output)
  k_gather_bf<<<(N + 3) / 4, 256, 0, stream>>>(hBb, rowptr, csr_src, aggb);
  k_sage_mfma<<<gsage, 256, 0, stream>>>(hBb, aggb, wt3, b_conv3, nullptr, out_h, N, 0);
}

// Round 6
// 435.648 us; speedup vs baseline: 4.7269x; 1.1912x over previous
//
#include <hip/hip_runtime.h>

#define N_NODES 50000
#define N_EDGES 800000
#define NF 128   // node feature dim
#define EH 32    // edge hidden
#define NB 128   // dst buckets for CSR sort
#define BN 391   // nodes per bucket (128*391 = 50048 >= 50000)
#define NCH 256  // edge chunks
#define CE 3125  // edges per chunk (256*3125 = 800000 exactly)

typedef __bf16 bf16x8 __attribute__((ext_vector_type(8)));
typedef float f32x4 __attribute__((ext_vector_type(4)));
typedef unsigned short u16x8 __attribute__((ext_vector_type(8)));
typedef unsigned short ushort_t;
typedef unsigned int uint_t;

__device__ inline ushort_t f2bf(float x) {
  uint_t u = __builtin_bit_cast(uint_t, x);
  return (ushort_t)((u + 0x7fffu + ((u >> 16) & 1u)) >> 16);
}
__device__ inline float blo(uint_t u) { return __builtin_bit_cast(float, u << 16); }
__device__ inline float bhi(uint_t u) { return __builtin_bit_cast(float, u & 0xffff0000u); }

// ---------------- CSR build: two-level bucket sort ----------------
// f1: per-chunk histogram over NB dst-buckets
__global__ __launch_bounds__(256) void f1_hist(const int* __restrict__ edst,
                                               int* __restrict__ ghist) {
  __shared__ int h[NB];
  int t = threadIdx.x, c = blockIdx.x;
  if (t < NB) h[t] = 0;
  __syncthreads();
  int base = c * CE;
  for (int i = t; i < CE; i += 256) atomicAdd(&h[edst[base + i] / BN], 1);
  __syncthreads();
  if (t < NB) ghist[t * NCH + c] = h[t];  // bucket-major
}

// f2: one-block exclusive scan of 128*256 = 32768 bucket-major counts
__global__ __launch_bounds__(1024) void f2_scan(int* __restrict__ g) {
  __shared__ int part[1024];
  int t = threadIdx.x;
  int base = t * 32;
  int loc[32];
  int s = 0;
  #pragma unroll
  for (int i = 0; i < 32; ++i) { loc[i] = g[base + i]; s += loc[i]; }
  part[t] = s;
  __syncthreads();
  for (int off = 1; off < 1024; off <<= 1) {
    int v = (t >= off) ? part[t - off] : 0;
    __syncthreads();
    part[t] += v;
    __syncthreads();
  }
  int run = part[t] - s;
  #pragma unroll
  for (int i = 0; i < 32; ++i) { int c = loc[i]; g[base + i] = run; run += c; }
}

// f3: bin packed (dst<<16|src) edges into bucket-major ebuf
__global__ __launch_bounds__(256) void f3_bin(const int* __restrict__ esrc,
                                              const int* __restrict__ edst,
                                              const int* __restrict__ gofs,
                                              uint_t* __restrict__ ebuf) {
  __shared__ int cur[NB];
  int t = threadIdx.x, c = blockIdx.x;
  if (t < NB) cur[t] = gofs[t * NCH + c];
  __syncthreads();
  int base = c * CE;
  for (int i = t; i < CE; i += 256) {
    int d = edst[base + i];
    int s = esrc[base + i];
    int p = atomicAdd(&cur[d / BN], 1);
    ebuf[p] = ((uint_t)d << 16) | (uint_t)s;
  }
}

// f4: per-bucket fine fill; also emits rowptr (replaces count+scan chain)
__global__ __launch_bounds__(256) void f4_fill(const uint_t* __restrict__ ebuf,
                                               const int* __restrict__ gofs,
                                               int* __restrict__ rowptr,
                                               int* __restrict__ csr_src) {
  __shared__ int cnt[392];
  __shared__ int cur[392];
  int b = blockIdx.x, t = threadIdx.x;
  int bstart = gofs[b * NCH];
  int bend = (b == NB - 1) ? N_EDGES : gofs[(b + 1) * NCH];
  int nbase = b * BN;
  for (int i = t; i < 392; i += 256) cnt[i] = 0;
  __syncthreads();
  for (int i = bstart + t; i < bend; i += 256)
    atomicAdd(&cnt[(ebuf[i] >> 16) - nbase], 1);
  __syncthreads();
  if (t < 64) {  // wave-0 exclusive scan of cnt[0..390]
    int carry = 0;
    for (int base = 0; base < 392; base += 64) {
      int i = base + t;
      int v = (i < 391) ? cnt[i] : 0;
      int x = v;
      #pragma unroll
      for (int off = 1; off < 64; off <<= 1) {
        int y = __shfl_up(x, off, 64);
        if (t >= off) x += y;
      }
      if (i < 392) cur[i] = x - v + carry;
      carry += __shfl(x, 63, 64);
    }
  }
  __syncthreads();
  for (int i = t; i < BN; i += 256) {
    int g = nbase + i;
    if (g < N_NODES) rowptr[g] = bstart + cur[i];
  }
  if (b == NB - 1 && t == 0) rowptr[N_NODES] = N_EDGES;
  __syncthreads();
  for (int i = bstart + t; i < bend; i += 256) {
    uint_t pk = ebuf[i];
    int p = atomicAdd(&cur[(pk >> 16) - nbase], 1);
    csr_src[bstart + p] = (int)(pk & 0xffffu);
  }
}

// ---------------- packed weight-prep + input cast ----------------
__global__ __launch_bounds__(256) void k_prepcast(
    const float* __restrict__ ws1, const float* __restrict__ wn1,
    const float* __restrict__ ws2, const float* __restrict__ wn2,
    const float* __restrict__ ws3, const float* __restrict__ wn3,
    const float* __restrict__ wu1, const float* __restrict__ wv1,
    const float* __restrict__ wu2, const float* __restrict__ wv2,
    ushort_t* __restrict__ wt1, ushort_t* __restrict__ wt2, ushort_t* __restrict__ wt3,
    ushort_t* __restrict__ wp1, ushort_t* __restrict__ wp2,
    const float* __restrict__ x, ushort_t* __restrict__ xb) {
  int blk = blockIdx.x;
  int t = threadIdx.x;
  if (blk < 448) {  // weight prep (114688 items)
    int i = blk * 256 + t;
    if (i < 98304) {
      int l = i >> 15;
      int j = i & 32767;
      int n = j >> 8, k = j & 255;
      const float* s = (l == 0) ? (k < 128 ? ws1 : wn1)
                     : (l == 1) ? (k < 128 ? ws2 : wn2)
                                : (k < 128 ? ws3 : wn3);
      float v = s[(k & 127) * 128 + n];
      ushort_t* d = (l == 0) ? wt1 : (l == 1) ? wt2 : wt3;
      d[n * 256 + k] = f2bf(v);
    } else if (i < 114688) {
      int j = i - 98304;
      int l = j >> 13;
      int m = j & 8191;
      int n = m >> 7, k = m & 127;
      const float* s = (l == 0) ? (n < 32 ? wu1 : wv1) : (n < 32 ? wu2 : wv2);
      float v = s[k * 32 + (n & 31)];
      ushort_t* d = (l == 0) ? wp1 : wp2;
      d[n * 128 + k] = f2bf(v);
    }
  } else {  // input cast: 1600000 float4 groups / 6250 blocks
    int i = (blk - 448) * 256 + t;
    float4 v = ((const float4*)x)[i];
    uint2 p;
    p.x = (uint_t)f2bf(v.x) | ((uint_t)f2bf(v.y) << 16);
    p.y = (uint_t)f2bf(v.z) | ((uint_t)f2bf(v.w) << 16);
    ((uint2*)xb)[i] = p;
  }
}

// ---------------- CSR mean-gather: half-wave per neighbor row ----------------
__global__ __launch_bounds__(256) void k_gather_bf(
    const ushort_t* __restrict__ hb, const int* __restrict__ rowptr,
    const int* __restrict__ csr_src, ushort_t* __restrict__ aggb) {
  int n = blockIdx.x * 4 + (threadIdx.x >> 6);
  if (n >= N_NODES) return;
  int lane = threadIdx.x & 63;
  int half = lane >> 5;
  int l32 = lane & 31;
  int beg = rowptr[n], end = rowptr[n + 1];
  float f0 = 0.f, f1 = 0.f, f2 = 0.f, f3 = 0.f;
  int j = beg;
  for (; j + 8 <= end; j += 8) {
    int sa = csr_src[j + half];
    int sb_ = csr_src[j + 2 + half];
    int sc = csr_src[j + 4 + half];
    int sd = csr_src[j + 6 + half];
    uint2 ua = *(const uint2*)&hb[sa * NF + l32 * 4];
    uint2 ub_ = *(const uint2*)&hb[sb_ * NF + l32 * 4];
    uint2 uc = *(const uint2*)&hb[sc * NF + l32 * 4];
    uint2 ud = *(const uint2*)&hb[sd * NF + l32 * 4];
    f0 += blo(ua.x) + blo(ub_.x) + blo(uc.x) + blo(ud.x);
    f1 += bhi(ua.x) + bhi(ub_.x) + bhi(uc.x) + bhi(ud.x);
    f2 += blo(ua.y) + blo(ub_.y) + blo(uc.y) + blo(ud.y);
    f3 += bhi(ua.y) + bhi(ub_.y) + bhi(uc.y) + bhi(ud.y);
  }
  for (; j + 2 <= end; j += 2) {
    int sa = csr_src[j + half];
    uint2 ua = *(const uint2*)&hb[sa * NF + l32 * 4];
    f0 += blo(ua.x); f1 += bhi(ua.x); f2 += blo(ua.y); f3 += bhi(ua.y);
  }
  if (j < end && half == 0) {
    int sa = csr_src[j];
    uint2 ua = *(const uint2*)&hb[sa * NF + l32 * 4];
    f0 += blo(ua.x); f1 += bhi(ua.x); f2 += blo(ua.y); f3 += bhi(ua.y);
  }
  f0 += __shfl_down(f0, 32, 64);
  f1 += __shfl_down(f1, 32, 64);
  f2 += __shfl_down(f2, 32, 64);
  f3 += __shfl_down(f3, 32, 64);
  if (half == 0) {
    int deg = end - beg;
    float inv = deg > 0 ? 1.0f / (float)deg : 0.f;
    uint2 p;
    p.x = (uint_t)f2bf(f0 * inv) | ((uint_t)f2bf(f1 * inv) << 16);
    p.y = (uint_t)f2bf(f2 * inv) | ((uint_t)f2bf(f3 * inv) << 16);
    *(uint2*)&aggb[n * NF + l32 * 4] = p;
  }
}

// ---------------- SAGE MFMA + fused edge projections ----------------
// Phase 1: out = act([h|agg] @ [Ws;Wn] + b). Phase 2 (if wp): write bf16 h-tile
// to LDS, compute [hu|hv] = h @ wp per wave (16-col slice).
__global__ __launch_bounds__(256) void k_sage_mfma(
    const ushort_t* __restrict__ xb, const ushort_t* __restrict__ ab,
    const ushort_t* __restrict__ wt,  // [128][256] bf16, k-contiguous
    const float* __restrict__ bias,
    ushort_t* __restrict__ out_bf, float* __restrict__ out_f32,
    const ushort_t* __restrict__ wp,  // [64][128] bf16 or nullptr
    ushort_t* __restrict__ hub, ushort_t* __restrict__ hvb,
    int M, int do_relu) {
  __shared__ ushort_t hs[64][136];  // pad 136: rows 272B (16B-mult), <=2-way conflicts
  int tid = threadIdx.x;
  int wave = tid >> 6, lane = tid & 63;
  int l16 = lane & 15, quad = lane >> 4;
  int row0 = blockIdx.x * 64;
  int n0 = wave * 32;
  f32x4 acc[4][2];
  #pragma unroll
  for (int a = 0; a < 4; ++a)
    #pragma unroll
    for (int b = 0; b < 2; ++b) acc[a][b] = (f32x4){0.f, 0.f, 0.f, 0.f};

  #pragma unroll
  for (int ks = 0; ks < 8; ++ks) {
    int k0 = ks * 32;
    const ushort_t* A = (ks < 4) ? xb : ab;
    int ka = (k0 & 127) + quad * 8;
    bf16x8 afr[4];
    #pragma unroll
    for (int mt = 0; mt < 4; ++mt) {
      int r = row0 + mt * 16 + l16;
      if (r >= M) r = M - 1;
      afr[mt] = __builtin_bit_cast(bf16x8, *(const u16x8*)&A[r * NF + ka]);
    }
    bf16x8 bfr[2];
    #pragma unroll
    for (int nt = 0; nt < 2; ++nt) {
      int n = n0 + nt * 16 + l16;
      bfr[nt] = __builtin_bit_cast(bf16x8, *(const u16x8*)&wt[n * 256 + k0 + quad * 8]);
    }
    #pragma unroll
    for (int mt = 0; mt < 4; ++mt)
      #pragma unroll
      for (int nt = 0; nt < 2; ++nt)
        acc[mt][nt] = __builtin_amdgcn_mfma_f32_16x16x32_bf16(
            afr[mt], bfr[nt], acc[mt][nt], 0, 0, 0);
  }

  #pragma unroll
  for (int nt = 0; nt < 2; ++nt) {
    int col = n0 + nt * 16 + l16;
    float bv = bias[col];
    #pragma unroll
    for (int mt = 0; mt < 4; ++mt) {
      #pragma unroll
      for (int reg = 0; reg < 4; ++reg) {
        int lr = mt * 16 + quad * 4 + reg;
        int r = row0 + lr;
        float v = acc[mt][nt][reg] + bv;
        if (do_relu) v = fmaxf(v, 0.f);
        if (r < M) {
          if (out_f32) out_f32[r * NF + col] = v;
          else         out_bf[r * NF + col] = f2bf(v);
        }
        if (wp) hs[lr][col] = f2bf(v);  // rows >= M hold junk; never stored later
      }
    }
  }

  if (wp) {
    __syncthreads();
    int nb2 = wave * 16;
    f32x4 pacc[4];
    #pragma unroll
    for (int a = 0; a < 4; ++a) pacc[a] = (f32x4){0.f, 0.f, 0.f, 0.f};
    #pragma unroll
    for (int ks = 0; ks < 4; ++ks) {
      int k0 = ks * 32;
      bf16x8 bfrp = __builtin_bit_cast(bf16x8,
          *(const u16x8*)&wp[(nb2 + l16) * NF + k0 + quad * 8]);
      #pragma unroll
      for (int mt = 0; mt < 4; ++mt) {
        bf16x8 afr = __builtin_bit_cast(bf16x8,
            *(const u16x8*)&hs[mt * 16 + l16][k0 + quad * 8]);
        pacc[mt] = __builtin_amdgcn_mfma_f32_16x16x32_bf16(afr, bfrp, pacc[mt], 0, 0, 0);
      }
    }
    int col = nb2 + l16;
    #pragma unroll
    for (int mt = 0; mt < 4; ++mt) {
      #pragma unroll
      for (int reg = 0; reg < 4; ++reg) {
        int r = row0 + mt * 16 + quad * 4 + reg;
        if (r < M) {
          ushort_t v = f2bf(pacc[mt][reg]);
          if (col < 32) hub[r * EH + col] = v;
          else          hvb[r * EH + col - 32] = v;
        }
      }
    }
  }
}

// ---------------- edge MLP, cooperative: 8 lanes per edge ----------------
template <int EFD>
__global__ __launch_bounds__(256) void k_edge(
    const ushort_t* __restrict__ hub, const ushort_t* __restrict__ hvb,
    const int* __restrict__ src, const int* __restrict__ dst,
    const float* __restrict__ ef, int ef_stride,
    const float* __restrict__ we, const float* __restrict__ b,
    const float* __restrict__ w2, const float* __restrict__ b2,
    float* __restrict__ out, int out_col,
    const float* __restrict__ copy_ef, int E) {
  __shared__ float swe[EFD][EH];
  __shared__ float sw2[EH][4];
  __shared__ float sb[EH];
  __shared__ float sb2v[4];
  int tid = threadIdx.x;
  for (int i = tid; i < EFD * EH; i += 256) swe[i >> 5][i & 31] = we[i];
  if (tid < EH * 4) sw2[tid >> 2][tid & 3] = w2[tid];
  if (tid < EH) sb[tid] = b[tid];
  if (tid < 4) sb2v[tid] = b2[tid];
  __syncthreads();
  int gi = blockIdx.x * 256 + tid;
  int e = gi >> 3;
  int q = gi & 7;
  if (e >= E) return;
  int s = src[e], d = dst[e];
  int cb = q * 4;
  uint2 au = *(const uint2*)&hub[s * EH + cb];
  uint2 av = *(const uint2*)&hvb[d * EH + cb];
  float efv[EFD];
  {
    float4 v = *(const float4*)&ef[(long long)e * ef_stride];
    efv[0] = v.x; efv[1] = v.y; efv[2] = v.z; efv[3] = v.w;
    if (EFD == 8) {
      float4 v1 = *(const float4*)&ef[(long long)e * ef_stride + 4];
      efv[4] = v1.x; efv[5] = v1.y; efv[6] = v1.z; efv[7] = v1.w;
    }
  }
  float t0 = blo(au.x) + blo(av.x) + sb[cb + 0];
  float t1 = bhi(au.x) + bhi(av.x) + sb[cb + 1];
  float t2 = blo(au.y) + blo(av.y) + sb[cb + 2];
  float t3 = bhi(au.y) + bhi(av.y) + sb[cb + 3];
  #pragma unroll
  for (int i = 0; i < EFD; ++i) {
    float efi = efv[i];
    t0 += efi * swe[i][cb + 0];
    t1 += efi * swe[i][cb + 1];
    t2 += efi * swe[i][cb + 2];
    t3 += efi * swe[i][cb + 3];
  }
  t0 = fmaxf(t0, 0.f); t1 = fmaxf(t1, 0.f);
  t2 = fmaxf(t2, 0.f); t3 = fmaxf(t3, 0.f);
  float o0 = t0 * sw2[cb + 0][0] + t1 * sw2[cb + 1][0] + t2 * sw2[cb + 2][0] + t3 * sw2[cb + 3][0];
  float o1 = t0 * sw2[cb + 0][1] + t1 * sw2[cb + 1][1] + t2 * sw2[cb + 2][1] + t3 * sw2[cb + 3][1];
  float o2 = t0 * sw2[cb + 0][2] + t1 * sw2[cb + 1][2] + t2 * sw2[cb + 2][2] + t3 * sw2[cb + 3][2];
  float o3 = t0 * sw2[cb + 0][3] + t1 * sw2[cb + 1][3] + t2 * sw2[cb + 2][3] + t3 * sw2[cb + 3][3];
  #pragma unroll
  for (int m = 4; m; m >>= 1) {
    o0 += __shfl_xor(o0, m, 64);
    o1 += __shfl_xor(o1, m, 64);
    o2 += __shfl_xor(o2, m, 64);
    o3 += __shfl_xor(o3, m, 64);
  }
  if (q == 0) {
    *(float4*)&out[(long long)e * 12 + out_col] =
        make_float4(o0 + sb2v[0], o1 + sb2v[1], o2 + sb2v[2], o3 + sb2v[3]);
  }
  if (copy_ef && q == 1) {
    *(float4*)&out[(long long)e * 12] = *(const float4*)&copy_ef[e * 4];
  }
}

// ---------------- launch ----------------
extern "C" void kernel_launch(void* const* d_in, const int* in_sizes, int n_in,
                              void* d_out, int out_size, void* d_ws, size_t ws_size,
                              hipStream_t stream) {
  const float* inputs    = (const float*)d_in[0];
  const float* edge_feat = (const float*)d_in[1];
  const float* w_self1   = (const float*)d_in[2];
  const float* w_neigh1  = (const float*)d_in[3];
  const float* b_conv1   = (const float*)d_in[4];
  const float* eu1_wu    = (const float*)d_in[5];
  const float* eu1_wv    = (const float*)d_in[6];
  const float* eu1_we    = (const float*)d_in[7];
  const float* eu1_b     = (const float*)d_in[8];
  const float* eu1_w2    = (const float*)d_in[9];
  const float* eu1_b2    = (const float*)d_in[10];
  const float* w_self2   = (const float*)d_in[11];
  const float* w_neigh2  = (const float*)d_in[12];
  const float* b_conv2   = (const float*)d_in[13];
  const float* eu2_wu    = (const float*)d_in[14];
  const float* eu2_wv    = (const float*)d_in[15];
  const float* eu2_we    = (const float*)d_in[16];
  const float* eu2_b     = (const float*)d_in[17];
  const float* eu2_w2    = (const float*)d_in[18];
  const float* eu2_b2    = (const float*)d_in[19];
  const float* w_self3   = (const float*)d_in[20];
  const float* w_neigh3  = (const float*)d_in[21];
  const float* b_conv3   = (const float*)d_in[22];
  const int*   esrc      = (const int*)d_in[23];
  const int*   edst      = (const int*)d_in[24];

  float* out_h  = (float*)d_out;                           // [N,128]
  float* out_ef = (float*)d_out + (long long)N_NODES * NF; // [E,12]

  // workspace: int region then bf16 region
  int* iws     = (int*)d_ws;
  int* gofs    = iws;                 // 32768 (NB*NCH)
  uint_t* ebuf = (uint_t*)(iws + 32768);  // 800000
  int* rowptr  = iws + 832768;        // 50001 (pad 50004) -> ends 882772
  int* csr_src = iws + 882784;        // 800000 -> ends 1682784
  ushort_t* ub = (ushort_t*)(iws + 1682784);  // byte off 6731136, %16==0
  ushort_t* xb   = ub;                        // N*128 = 6.4e6
  ushort_t* hAb  = ub + 6400000;
  ushort_t* hBb  = ub + 12800000;
  ushort_t* aggb = ub + 19200000;
  ushort_t* wt1  = ub + 25600000;             // 32768 each
  ushort_t* wt2  = ub + 25632768;
  ushort_t* wt3  = ub + 25665536;
  ushort_t* wp1  = ub + 25698304;             // 8192 each
  ushort_t* wp2  = ub + 25706496;
  // hu/hv layer1 alias hBb (hBb not written until L2 sage, after L1 edge done)
  ushort_t* hub1 = hBb;
  ushort_t* hvb1 = hBb + (long long)N_NODES * EH;
  // hu/hv layer2 alias xb (xb dead after L1 sage reads it)
  ushort_t* hub2 = xb;
  ushort_t* hvb2 = xb + (long long)N_NODES * EH;

  const int N = N_NODES, E = N_EDGES;
  int gsage = (N + 63) / 64;  // 782
  int gedge = (E * 8) / 256;  // 25000 exactly

  // ---- weight prep + input cast (packed), CSR bucket sort
  k_prepcast<<<448 + 6250, 256, 0, stream>>>(
      w_self1, w_neigh1, w_self2, w_neigh2, w_self3, w_neigh3,
      eu1_wu, eu1_wv, eu2_wu, eu2_wv,
      wt1, wt2, wt3, wp1, wp2, inputs, xb);
  f1_hist<<<NCH, 256, 0, stream>>>(edst, gofs);
  f2_scan<<<1, 1024, 0, stream>>>(gofs);
  f3_bin<<<NCH, 256, 0, stream>>>(esrc, edst, gofs, ebuf);
  f4_fill<<<NB, 256, 0, stream>>>(ebuf, gofs, rowptr, csr_src);

  // ---- layer 1
  k_gather_bf<<<(N + 3) / 4, 256, 0, stream>>>(xb, rowptr, csr_src, aggb);
  k_sage_mfma<<<gsage, 256, 0, stream>>>(xb, aggb, wt1, b_conv1, hAb, nullptr,
                                         wp1, hub1, hvb1, N, 1);
  k_edge<4><<<gedge, 256, 0, stream>>>(
      hub1, hvb1, esrc, edst, edge_feat, 4, eu1_we, eu1_b, eu1_w2, eu1_b2,
      out_ef, 4, edge_feat, E);

  // ---- layer 2
  k_gather_bf<<<(N + 3) / 4, 256, 0, stream>>>(hAb, rowptr, csr_src, aggb);
  k_sage_mfma<<<gsage, 256, 0, stream>>>(hAb, aggb, wt2, b_conv2, hBb, nullptr,
                                         wp2, hub2, hvb2, N, 1);
  k_edge<8><<<gedge, 256, 0, stream>>>(
      hub2, hvb2, esrc, edst, out_ef, 12, eu2_we, eu2_b, eu2_w2, eu2_b2,
      out_ef, 8, nullptr, E);

  // ---- layer 3 (no relu, fp32 output, no proj)
  k_gather_bf<<<(N + 3) / 4, 256, 0, stream>>>(hBb, rowptr, csr_src, aggb);
  k_sage_mfma<<<gsage, 256, 0, stream>>>(hBb, aggb, wt3, b_conv3, nullptr, out_h,
                                         nullptr, nullptr, nullptr, N, 0);
}